// Round 1
// baseline (1945.153 us; speedup 1.0000x reference)
//
#include <hip/hip_runtime.h>
#include <cstdint>

// Problem constants
constexpr int BB   = 2;
constexpr int SS   = 2048;
constexpr int DD   = 768;
constexpr int HH   = 12;
constexpr int NTOK = BB * SS;          // 4096
constexpr int KSEL = 409;              // int((1-0.8)*2048)

typedef __bf16 bf16x8 __attribute__((ext_vector_type(8)));
typedef float  f32x4  __attribute__((ext_vector_type(4)));

__device__ __forceinline__ float b2f(unsigned short u) {
  return __uint_as_float(((unsigned)u) << 16);
}
__device__ __forceinline__ unsigned short f2b(float f) {
  unsigned u = __float_as_uint(f);
  u += 0x7fffu + ((u >> 16) & 1u);   // RNE
  return (unsigned short)(u >> 16);
}

__device__ __forceinline__ void gload_lds16(const void* gsrc, void* ldst) {
  __builtin_amdgcn_global_load_lds(
      (__attribute__((address_space(1))) void*)(gsrc),
      (__attribute__((address_space(3))) void*)(ldst), 16, 0, 0);
}

// ---------------- prep: xb = bf16(x); xpb = bf16(x + pos_encoding) ----------
__global__ __launch_bounds__(256) void prep_x(const float* __restrict__ x,
                                              unsigned short* __restrict__ xb,
                                              unsigned short* __restrict__ xpb) {
  long i = (long)blockIdx.x * 256 + threadIdx.x;      // over NTOK*DD
  float xv = x[i];
  int c = (int)(i % DD);
  int srow = (int)((i / DD) & (SS - 1));
  xb[i] = f2b(xv);
  int j2 = c & ~1;
  float freq = __expf((float)j2 * -0.011992630692677323f);  // exp(-j2*ln(1e4)/768)
  float ang = (float)srow * freq;
  float pe = (c & 1) ? cosf(ang) : sinf(ang);
  xpb[i] = f2b(xv + pe);
}

// ---------------- transpose all weights to bf16 B^T (N x K) -----------------
__global__ void transpose_all(const float* w0, const float* w1, const float* w2,
                              const float* w3, const float* w4, const float* w5,
                              const float* w6, const float* w7, const float* w8,
                              const float* w9,
                              unsigned short* WTx, unsigned short* WTt,
                              unsigned short* WTo) {
  __shared__ float tile[32][33];
  int z = blockIdx.z;
  const float* src;
  unsigned short* dst;
  int R;
  if (z < 6)      { const float* a[6] = {w0,w1,w2,w3,w4,w5}; src = a[z];   dst = WTx + (long)z*DD*DD;     R = DD;   }
  else if (z < 9) { const float* a[3] = {w6,w7,w8};          src = a[z-6]; dst = WTt + (long)(z-6)*DD*DD; R = DD;   }
  else            { src = w9; dst = WTo; R = 2304; }
  int r0 = blockIdx.y * 32;
  if (r0 >= R) return;
  int c0 = blockIdx.x * 32;
  int tx = threadIdx.x, ty = threadIdx.y;
  for (int i = ty; i < 32; i += 8) tile[i][tx] = src[(long)(r0 + i) * DD + c0 + tx];
  __syncthreads();
  for (int i = ty; i < 32; i += 8) dst[(long)(c0 + i) * R + r0 + tx] = f2b(tile[tx][i]);
}

// ---------------- importance = x @ w_sparse + b ------------------------------
__global__ __launch_bounds__(256) void imp_kernel(const float* __restrict__ x,
                                                  const float* __restrict__ wsp,
                                                  const float* __restrict__ bsp,
                                                  float* __restrict__ imp) {
  int row = blockIdx.x * 4 + (threadIdx.x >> 6);
  int lane = threadIdx.x & 63;
  const float* xp = x + (long)row * DD;
  float acc = 0.f;
  for (int d = lane; d < DD; d += 64) acc += xp[d] * wsp[d];
#pragma unroll
  for (int m = 1; m < 64; m <<= 1) acc += __shfl_xor(acc, m, 64);
  if (lane == 0) imp[row] = acc + bsp[0];
}

// ---------------- top-k via bitonic sort (value desc, index asc) ------------
__global__ __launch_bounds__(1024) void topk_kernel(const float* __restrict__ imp,
                                                    int* __restrict__ sel) {
  __shared__ unsigned long long keys[SS];
  int b = blockIdx.x, tid = threadIdx.x;
  for (int i = tid; i < SS; i += 1024) {
    float v = imp[b * SS + i];
    unsigned u = __float_as_uint(v);
    u = (u & 0x80000000u) ? ~u : (u | 0x80000000u);   // ascending-order map
    unsigned du = ~u;                                  // descending
    keys[i] = ((unsigned long long)du << 32) | (unsigned)i;
  }
  __syncthreads();
  for (int k = 2; k <= SS; k <<= 1) {
    for (int j = k >> 1; j > 0; j >>= 1) {
      for (int i = tid; i < SS; i += 1024) {
        int p = i ^ j;
        if (p > i) {
          unsigned long long a = keys[i], bb = keys[p];
          bool up = ((i & k) == 0);
          if ((a > bb) == up) { keys[i] = bb; keys[p] = a; }
        }
      }
      __syncthreads();
    }
  }
  for (int i = tid; i < KSEL; i += 1024) sel[b * KSEL + i] = (int)(keys[i] & 0xffffffffu);
}

// ---------------- gate: mean over s, then softmax(mean @ w_gate + b) --------
__global__ __launch_bounds__(256) void gate1(const float* __restrict__ x,
                                             float* __restrict__ partial) {
  int b = blockIdx.y, chunk = blockIdx.x, tid = threadIdx.x;
  for (int c = tid; c < DD; c += 256) {
    const float* xp = x + ((long)(b * SS + chunk * 128)) * DD + c;
    float acc = 0.f;
    for (int s2 = 0; s2 < 128; ++s2) acc += xp[(long)s2 * DD];
    partial[(long)(b * 16 + chunk) * DD + c] = acc;
  }
}

__global__ __launch_bounds__(256) void gate2(const float* __restrict__ partial,
                                             const float* __restrict__ w_gate,
                                             const float* __restrict__ b_gate,
                                             float* __restrict__ fw) {
  int b = blockIdx.x, tid = threadIdx.x;
  __shared__ float meanbuf[DD];
  __shared__ float lg[3];
  for (int c = tid; c < DD; c += 256) {
    float acc = 0.f;
    for (int p = 0; p < 16; ++p) acc += partial[(long)(b * 16 + p) * DD + c];
    meanbuf[c] = acc * (1.0f / (float)SS);
  }
  __syncthreads();
  if (tid < 3) {
    float acc = b_gate[tid];
    for (int d = 0; d < DD; ++d) acc += meanbuf[d] * w_gate[d * 3 + tid];
    lg[tid] = acc;
  }
  __syncthreads();
  if (tid == 0) {
    float mx = fmaxf(lg[0], fmaxf(lg[1], lg[2]));
    float e0 = expf(lg[0] - mx), e1 = expf(lg[1] - mx), e2 = expf(lg[2] - mx);
    float inv = 1.f / (e0 + e1 + e2);
    fw[b * 3 + 0] = e0 * inv; fw[b * 3 + 1] = e1 * inv; fw[b * 3 + 2] = e2 * inv;
  }
}

// ---------------- MFMA GEMM: C = A(MxK) * BT(NxK)^T --------------------------
// 128x128 tile, BK=32, 4 waves (2x2), 16x16x32 bf16 MFMA.
// LDS XOR-swizzle (slot ^= (row>>1)&3) applied on staging SOURCE + read addr.
template <int OUT_BF16>
__global__ __launch_bounds__(256) void gemm_tile(const unsigned short* __restrict__ A,
                                                 const unsigned short* __restrict__ BT,
                                                 void* __restrict__ C,
                                                 const float* __restrict__ bias,
                                                 int N, int K) {
  __shared__ unsigned short As[128 * 32];
  __shared__ unsigned short Bs[128 * 32];
  const int tid = threadIdx.x;
  const int lane = tid & 63;
  const int wv = tid >> 6;
  const int wr = wv >> 1, wc = wv & 1;
  const long rowBase = (long)blockIdx.y * 128;
  const long colBase = (long)blockIdx.x * 128;

  f32x4 acc[4][4];
#pragma unroll
  for (int i = 0; i < 4; ++i)
#pragma unroll
    for (int j = 0; j < 4; ++j)
#pragma unroll
      for (int r = 0; r < 4; ++r) acc[i][j][r] = 0.f;

  const int g0 = tid, g1 = tid + 256;
  const int r0 = g0 >> 2, k80 = (g0 & 3) ^ ((r0 >> 1) & 3);
  const int r1 = g1 >> 2, k81 = (g1 & 3) ^ ((r1 >> 1) & 3);
  const unsigned short* ga0 = A + (rowBase + r0) * (long)K + k80 * 8;
  const unsigned short* ga1 = A + (rowBase + r1) * (long)K + k81 * 8;
  const unsigned short* gb0 = BT + (colBase + r0) * (long)K + k80 * 8;
  const unsigned short* gb1 = BT + (colBase + r1) * (long)K + k81 * 8;
  unsigned short* la0 = As + g0 * 8;
  unsigned short* la1 = As + g1 * 8;
  unsigned short* lb0 = Bs + g0 * 8;
  unsigned short* lb1 = Bs + g1 * 8;

  const int k8 = lane >> 4;
  const int fr = lane & 15;
  int aoff[4], boff[4];
#pragma unroll
  for (int i = 0; i < 4; ++i) {
    int rowA = wr * 64 + i * 16 + fr;
    aoff[i] = (rowA * 4 + (k8 ^ ((rowA >> 1) & 3))) * 8;
    int rowB = wc * 64 + i * 16 + fr;
    boff[i] = (rowB * 4 + (k8 ^ ((rowB >> 1) & 3))) * 8;
  }

  for (int kt = 0; kt < K; kt += 32) {
    gload_lds16(ga0 + kt, la0);
    gload_lds16(ga1 + kt, la1);
    gload_lds16(gb0 + kt, lb0);
    gload_lds16(gb1 + kt, lb1);
    __syncthreads();
    bf16x8 af[4], bfr[4];
#pragma unroll
    for (int i = 0; i < 4; ++i) af[i] = *(const bf16x8*)(As + aoff[i]);
#pragma unroll
    for (int i = 0; i < 4; ++i) bfr[i] = *(const bf16x8*)(Bs + boff[i]);
#pragma unroll
    for (int mi = 0; mi < 4; ++mi)
#pragma unroll
      for (int ni = 0; ni < 4; ++ni)
        acc[mi][ni] = __builtin_amdgcn_mfma_f32_16x16x32_bf16(af[mi], bfr[ni], acc[mi][ni], 0, 0, 0);
    __syncthreads();
  }

  const int orow0 = (lane >> 4) * 4;
#pragma unroll
  for (int mi = 0; mi < 4; ++mi) {
    long gr = rowBase + wr * 64 + mi * 16 + orow0;
#pragma unroll
    for (int ni = 0; ni < 4; ++ni) {
      long gc = colBase + wc * 64 + ni * 16 + fr;
#pragma unroll
      for (int r = 0; r < 4; ++r) {
        float v = acc[mi][ni][r];
        if (OUT_BF16) {
          ((unsigned short*)C)[(gr + r) * (long)N + gc] = f2b(v);
        } else {
          ((float*)C)[(gr + r) * (long)N + gc] = v + bias[gc];
        }
      }
    }
  }
}

// ---------------- masked attention, online softmax, one wave per query ------
// MODE 0: local window +-8; MODE 1: temporal cols j*256; MODE 2: sel[] list
template <int MODE>
__global__ __launch_bounds__(256) void attn_kernel(const unsigned short* __restrict__ QKV,
                                                   int ld, int qo, int ko, int vo,
                                                   const int* __restrict__ sel,
                                                   float* __restrict__ Outp) {
  int slot = blockIdx.x * 4 + (threadIdx.x >> 6);
  int lane = threadIdx.x & 63;
  int b = slot / (HH * SS);
  int rem = slot - b * (HH * SS);
  int h = rem / SS;
  int q = rem - h * SS;
  long rowq = (long)b * SS + q;
  int hoff = h * 64;
  float qv = b2f(QKV[rowq * ld + qo + hoff + lane]);
  float m = -3.4e38f, lsum = 0.f, o = 0.f;

  auto body = [&](int j) {
    long rk = (long)b * SS + j;
    float p = qv * b2f(QKV[rk * ld + ko + hoff + lane]);
    p += __shfl_xor(p, 1, 64);
    p += __shfl_xor(p, 2, 64);
    p += __shfl_xor(p, 4, 64);
    p += __shfl_xor(p, 8, 64);
    p += __shfl_xor(p, 16, 64);
    p += __shfl_xor(p, 32, 64);
    float s = p * 0.125f;                       // / sqrt(64)
    float vv = b2f(QKV[rk * ld + vo + hoff + lane]);
    if (s > m) {                                 // wave-uniform
      float cc = __expf(m - s);
      lsum *= cc; o *= cc; m = s;
    }
    float e = __expf(s - m);
    lsum += e; o += e * vv;
  };

  if (MODE == 0) {
    int j0 = q - 8; if (j0 < 0) j0 = 0;
    int j1 = q + 8; if (j1 > SS - 1) j1 = SS - 1;
    for (int j = j0; j <= j1; ++j) body(j);
  } else if (MODE == 1) {
#pragma unroll
    for (int t = 0; t < 8; ++t) body(t * 256);
  } else {
    for (int it = 0; it < KSEL; ++it) body(sel[b * KSEL + it]);
  }
  Outp[rowq * DD + hoff + lane] = o / lsum;
}

// ---------------- layernorm + gate scale + concat to bf16 -------------------
__global__ __launch_bounds__(256) void ln_gate_concat(
    const float* __restrict__ gsrc, const float* __restrict__ lsrc, const float* __restrict__ tsrc,
    const float* __restrict__ gg, const float* __restrict__ gb,
    const float* __restrict__ lgam, const float* __restrict__ lbet,
    const float* __restrict__ tg, const float* __restrict__ tb,
    const float* __restrict__ fw, unsigned short* __restrict__ comb) {
  int row = blockIdx.x;
  int b = row >> 11;
  int tid = threadIdx.x;
  __shared__ float red[8];
  const float* srcs[3] = {gsrc, lsrc, tsrc};
  const float* gams[3] = {gg, lgam, tg};
  const float* bets[3] = {gb, lbet, tb};
#pragma unroll
  for (int br = 0; br < 3; ++br) {
    const float* src = srcs[br] + (long)row * DD;
    float x0 = src[tid], x1 = src[tid + 256], x2 = src[tid + 512];
    float s = x0 + x1 + x2;
    float ss = x0 * x0 + x1 * x1 + x2 * x2;
#pragma unroll
    for (int msk = 1; msk < 64; msk <<= 1) {
      s += __shfl_xor(s, msk, 64);
      ss += __shfl_xor(ss, msk, 64);
    }
    int wv = tid >> 6, lane = tid & 63;
    if (lane == 0) { red[wv] = s; red[4 + wv] = ss; }
    __syncthreads();
    float S4 = red[0] + red[1] + red[2] + red[3];
    float SQ = red[4] + red[5] + red[6] + red[7];
    float mean = S4 * (1.f / (float)DD);
    float var = SQ * (1.f / (float)DD) - mean * mean;
    float rs = rsqrtf(var + 1e-5f);
    float gate = fw[b * 3 + br];
    const float* gam = gams[br];
    const float* bet = bets[br];
    unsigned short* dst = comb + (long)row * 2304 + br * DD;
    dst[tid]       = f2b(((x0 - mean) * rs * gam[tid]       + bet[tid])       * gate);
    dst[tid + 256] = f2b(((x1 - mean) * rs * gam[tid + 256] + bet[tid + 256]) * gate);
    dst[tid + 512] = f2b(((x2 - mean) * rs * gam[tid + 512] + bet[tid + 512]) * gate);
    __syncthreads();
  }
}

// ---------------- launcher ---------------------------------------------------
extern "C" void kernel_launch(void* const* d_in, const int* in_sizes, int n_in,
                              void* d_out, int out_size, void* d_ws, size_t ws_size,
                              hipStream_t stream) {
  const float* x        = (const float*)d_in[0];
  const float* wgq      = (const float*)d_in[1];
  const float* wgk      = (const float*)d_in[2];
  const float* wgv      = (const float*)d_in[3];
  const float* wlq      = (const float*)d_in[4];
  const float* wlk      = (const float*)d_in[5];
  const float* wlv      = (const float*)d_in[6];
  const float* wtq      = (const float*)d_in[7];
  const float* wtk      = (const float*)d_in[8];
  const float* wtv      = (const float*)d_in[9];
  const float* w_out    = (const float*)d_in[10];
  const float* b_out    = (const float*)d_in[11];
  const float* w_gate   = (const float*)d_in[12];
  const float* b_gate   = (const float*)d_in[13];
  const float* w_sparse = (const float*)d_in[14];
  const float* b_sparse = (const float*)d_in[15];
  const float* g_gamma  = (const float*)d_in[16];
  const float* g_beta   = (const float*)d_in[17];
  const float* l_gamma  = (const float*)d_in[18];
  const float* l_beta   = (const float*)d_in[19];
  const float* t_gamma  = (const float*)d_in[20];
  const float* t_beta   = (const float*)d_in[21];
  float* outp = (float*)d_out;

  unsigned short* xb   = (unsigned short*)d_ws;
  unsigned short* xpb  = xb  + (long)NTOK * DD;
  unsigned short* WTx  = xpb + (long)NTOK * DD;
  unsigned short* WTt  = WTx + (long)4608 * DD;
  unsigned short* WTo  = WTt + (long)2304 * DD;
  unsigned short* QKVx = WTo + (long)DD * 2304;
  unsigned short* QKVt = QKVx + (long)NTOK * 4608;
  unsigned short* comb = QKVt + (long)NTOK * 2304;
  float* gout    = (float*)(comb + (long)NTOK * 2304);
  float* lout    = gout + (long)NTOK * DD;
  float* tout    = lout + (long)NTOK * DD;
  float* imp     = tout + (long)NTOK * DD;
  float* partial = imp + NTOK;
  float* fw      = partial + 32 * DD;
  int*   sel     = (int*)(fw + 8);

  prep_x<<<NTOK * DD / 256, 256, 0, stream>>>(x, xb, xpb);
  transpose_all<<<dim3(24, 72, 10), dim3(32, 8), 0, stream>>>(
      wgq, wgk, wgv, wlq, wlk, wlv, wtq, wtk, wtv, w_out, WTx, WTt, WTo);
  imp_kernel<<<NTOK / 4, 256, 0, stream>>>(x, w_sparse, b_sparse, imp);
  topk_kernel<<<BB, 1024, 0, stream>>>(imp, sel);
  gate1<<<dim3(16, BB), 256, 0, stream>>>(x, partial);
  gate2<<<BB, 256, 0, stream>>>(partial, w_gate, b_gate, fw);

  gemm_tile<1><<<dim3(36, 32), 256, 0, stream>>>(xb,  WTx, QKVx, nullptr, 4608, DD);
  gemm_tile<1><<<dim3(18, 32), 256, 0, stream>>>(xpb, WTt, QKVt, nullptr, 2304, DD);

  attn_kernel<2><<<NTOK * HH / 4, 256, 0, stream>>>(QKVx, 4608, 0,    768,  1536, sel,     gout);
  attn_kernel<0><<<NTOK * HH / 4, 256, 0, stream>>>(QKVx, 4608, 2304, 3072, 3840, nullptr, lout);
  attn_kernel<1><<<NTOK * HH / 4, 256, 0, stream>>>(QKVt, 2304, 0,    768,  1536, nullptr, tout);

  ln_gate_concat<<<NTOK, 256, 0, stream>>>(gout, lout, tout, g_gamma, g_beta,
                                           l_gamma, l_beta, t_gamma, t_beta, fw, comb);
  gemm_tile<0><<<dim3(6, 32), 256, 0, stream>>>(comb, WTo, outp, b_out, DD, 2304);
}

// Round 4
// 387.693 us; speedup vs baseline: 5.0173x; 5.0173x over previous
//
#include <hip/hip_runtime.h>
#include <cstdint>

// Problem constants
constexpr int BB   = 2;
constexpr int SS   = 2048;
constexpr int DD   = 768;
constexpr int HH   = 12;
constexpr int NTOK = BB * SS;          // 4096
constexpr int KSEL = 409;              // int((1-0.8)*2048)
constexpr int KPAD = 416;              // 26*16
constexpr int PSTR = 424;              // P_lds stride (16B-aligned rows, free 2-way)

typedef __bf16 bf16x8 __attribute__((ext_vector_type(8)));
typedef float  f32x4  __attribute__((ext_vector_type(4)));

__device__ __forceinline__ float b2f(unsigned short u) {
  return __uint_as_float(((unsigned)u) << 16);
}
__device__ __forceinline__ unsigned short f2b(float f) {
  unsigned u = __float_as_uint(f);
  u += 0x7fffu + ((u >> 16) & 1u);   // RNE
  return (unsigned short)(u >> 16);
}

__device__ __forceinline__ void gload_lds16(const void* gsrc, void* ldst) {
  __builtin_amdgcn_global_load_lds(
      (__attribute__((address_space(1))) void*)(gsrc),
      (__attribute__((address_space(3))) void*)(ldst), 16, 0, 0);
}

// ---------------- prep: xb = bf16(x); xpb = bf16(x + pos_encoding) ----------
__global__ __launch_bounds__(256) void prep_x(const float* __restrict__ x,
                                              unsigned short* __restrict__ xb,
                                              unsigned short* __restrict__ xpb) {
  long i = (long)blockIdx.x * 256 + threadIdx.x;      // over NTOK*DD
  float xv = x[i];
  int c = (int)(i % DD);
  int srow = (int)((i / DD) & (SS - 1));
  xb[i] = f2b(xv);
  int j2 = c & ~1;
  float freq = __expf((float)j2 * -0.011992630692677323f);  // exp(-j2*ln(1e4)/768)
  float ang = (float)srow * freq;
  float pe = (c & 1) ? cosf(ang) : sinf(ang);
  xpb[i] = f2b(xv + pe);
}

// ---------------- transpose all weights to bf16 B^T (N x K) -----------------
__global__ void transpose_all(const float* w0, const float* w1, const float* w2,
                              const float* w3, const float* w4, const float* w5,
                              const float* w6, const float* w7, const float* w8,
                              const float* w9,
                              unsigned short* WTx, unsigned short* WTt,
                              unsigned short* WTo) {
  __shared__ float tile[32][33];
  int z = blockIdx.z;
  const float* src;
  unsigned short* dst;
  int R;
  if (z < 6)      { const float* a[6] = {w0,w1,w2,w3,w4,w5}; src = a[z];   dst = WTx + (long)z*DD*DD;     R = DD;   }
  else if (z < 9) { const float* a[3] = {w6,w7,w8};          src = a[z-6]; dst = WTt + (long)(z-6)*DD*DD; R = DD;   }
  else            { src = w9; dst = WTo; R = 2304; }
  int r0 = blockIdx.y * 32;
  if (r0 >= R) return;
  int c0 = blockIdx.x * 32;
  int tx = threadIdx.x, ty = threadIdx.y;
  for (int i = ty; i < 32; i += 8) tile[i][tx] = src[(long)(r0 + i) * DD + c0 + tx];
  __syncthreads();
  for (int i = ty; i < 32; i += 8) dst[(long)(c0 + i) * R + r0 + tx] = f2b(tile[tx][i]);
}

// ---------------- importance = x @ w_sparse + b ------------------------------
__global__ __launch_bounds__(256) void imp_kernel(const float* __restrict__ x,
                                                  const float* __restrict__ wsp,
                                                  const float* __restrict__ bsp,
                                                  float* __restrict__ imp) {
  int row = blockIdx.x * 4 + (threadIdx.x >> 6);
  int lane = threadIdx.x & 63;
  const float* xp = x + (long)row * DD;
  float acc = 0.f;
  for (int d = lane; d < DD; d += 64) acc += xp[d] * wsp[d];
#pragma unroll
  for (int m = 1; m < 64; m <<= 1) acc += __shfl_xor(acc, m, 64);
  if (lane == 0) imp[row] = acc + bsp[0];
}

// ---------------- top-k via bitonic sort (value desc, index asc) ------------
__global__ __launch_bounds__(1024) void topk_kernel(const float* __restrict__ imp,
                                                    int* __restrict__ sel) {
  __shared__ unsigned long long keys[SS];
  int b = blockIdx.x, tid = threadIdx.x;
  for (int i = tid; i < SS; i += 1024) {
    float v = imp[b * SS + i];
    unsigned u = __float_as_uint(v);
    u = (u & 0x80000000u) ? ~u : (u | 0x80000000u);   // ascending-order map
    unsigned du = ~u;                                  // descending
    keys[i] = ((unsigned long long)du << 32) | (unsigned)i;
  }
  __syncthreads();
  for (int k = 2; k <= SS; k <<= 1) {
    for (int j = k >> 1; j > 0; j >>= 1) {
      for (int i = tid; i < SS; i += 1024) {
        int p = i ^ j;
        if (p > i) {
          unsigned long long a = keys[i], bb = keys[p];
          bool up = ((i & k) == 0);
          if ((a > bb) == up) { keys[i] = bb; keys[p] = a; }
        }
      }
      __syncthreads();
    }
  }
  for (int i = tid; i < KSEL; i += 1024) sel[b * KSEL + i] = (int)(keys[i] & 0xffffffffu);
}

// ---------------- gate: mean over s, then softmax(mean @ w_gate + b) --------
__global__ __launch_bounds__(256) void gate1(const float* __restrict__ x,
                                             float* __restrict__ partial) {
  int b = blockIdx.y, chunk = blockIdx.x, tid = threadIdx.x;
  for (int c = tid; c < DD; c += 256) {
    const float* xp = x + ((long)(b * SS + chunk * 128)) * DD + c;
    float acc = 0.f;
    for (int s2 = 0; s2 < 128; ++s2) acc += xp[(long)s2 * DD];
    partial[(long)(b * 16 + chunk) * DD + c] = acc;
  }
}

__global__ __launch_bounds__(256) void gate2(const float* __restrict__ partial,
                                             const float* __restrict__ w_gate,
                                             const float* __restrict__ b_gate,
                                             float* __restrict__ fw) {
  int b = blockIdx.x, tid = threadIdx.x;
  __shared__ float meanbuf[DD];
  __shared__ float lg[3];
  for (int c = tid; c < DD; c += 256) {
    float acc = 0.f;
    for (int p = 0; p < 16; ++p) acc += partial[(long)(b * 16 + p) * DD + c];
    meanbuf[c] = acc * (1.0f / (float)SS);
  }
  __syncthreads();
  if (tid < 3) {
    float acc = b_gate[tid];
    for (int d = 0; d < DD; ++d) acc += meanbuf[d] * w_gate[d * 3 + tid];
    lg[tid] = acc;
  }
  __syncthreads();
  if (tid == 0) {
    float mx = fmaxf(lg[0], fmaxf(lg[1], lg[2]));
    float e0 = expf(lg[0] - mx), e1 = expf(lg[1] - mx), e2 = expf(lg[2] - mx);
    float inv = 1.f / (e0 + e1 + e2);
    fw[b * 3 + 0] = e0 * inv; fw[b * 3 + 1] = e1 * inv; fw[b * 3 + 2] = e2 * inv;
  }
}

// ---------------- MFMA GEMM: C = A(MxK) * BT(NxK)^T --------------------------
template <int OUT_BF16>
__global__ __launch_bounds__(256) void gemm_tile(const unsigned short* __restrict__ A,
                                                 const unsigned short* __restrict__ BT,
                                                 void* __restrict__ C,
                                                 const float* __restrict__ bias,
                                                 int N, int K) {
  __shared__ unsigned short As[128 * 32];
  __shared__ unsigned short Bs[128 * 32];
  const int tid = threadIdx.x;
  const int lane = tid & 63;
  const int wv = tid >> 6;
  const int wr = wv >> 1, wc = wv & 1;
  const long rowBase = (long)blockIdx.y * 128;
  const long colBase = (long)blockIdx.x * 128;

  f32x4 acc[4][4];
#pragma unroll
  for (int i = 0; i < 4; ++i)
#pragma unroll
    for (int j = 0; j < 4; ++j)
#pragma unroll
      for (int r = 0; r < 4; ++r) acc[i][j][r] = 0.f;

  const int g0 = tid, g1 = tid + 256;
  const int r0 = g0 >> 2, k80 = (g0 & 3) ^ ((r0 >> 1) & 3);
  const int r1 = g1 >> 2, k81 = (g1 & 3) ^ ((r1 >> 1) & 3);
  const unsigned short* ga0 = A + (rowBase + r0) * (long)K + k80 * 8;
  const unsigned short* ga1 = A + (rowBase + r1) * (long)K + k81 * 8;
  const unsigned short* gb0 = BT + (colBase + r0) * (long)K + k80 * 8;
  const unsigned short* gb1 = BT + (colBase + r1) * (long)K + k81 * 8;
  unsigned short* la0 = As + g0 * 8;
  unsigned short* la1 = As + g1 * 8;
  unsigned short* lb0 = Bs + g0 * 8;
  unsigned short* lb1 = Bs + g1 * 8;

  const int k8 = lane >> 4;
  const int fr = lane & 15;
  int aoff[4], boff[4];
#pragma unroll
  for (int i = 0; i < 4; ++i) {
    int rowA = wr * 64 + i * 16 + fr;
    aoff[i] = (rowA * 4 + (k8 ^ ((rowA >> 1) & 3))) * 8;
    int rowB = wc * 64 + i * 16 + fr;
    boff[i] = (rowB * 4 + (k8 ^ ((rowB >> 1) & 3))) * 8;
  }

  for (int kt = 0; kt < K; kt += 32) {
    gload_lds16(ga0 + kt, la0);
    gload_lds16(ga1 + kt, la1);
    gload_lds16(gb0 + kt, lb0);
    gload_lds16(gb1 + kt, lb1);
    __syncthreads();
    bf16x8 af[4], bfr[4];
#pragma unroll
    for (int i = 0; i < 4; ++i) af[i] = *(const bf16x8*)(As + aoff[i]);
#pragma unroll
    for (int i = 0; i < 4; ++i) bfr[i] = *(const bf16x8*)(Bs + boff[i]);
#pragma unroll
    for (int mi = 0; mi < 4; ++mi)
#pragma unroll
      for (int ni = 0; ni < 4; ++ni)
        acc[mi][ni] = __builtin_amdgcn_mfma_f32_16x16x32_bf16(af[mi], bfr[ni], acc[mi][ni], 0, 0, 0);
    __syncthreads();
  }

  const int orow0 = (lane >> 4) * 4;
#pragma unroll
  for (int mi = 0; mi < 4; ++mi) {
    long gr = rowBase + wr * 64 + mi * 16 + orow0;
#pragma unroll
    for (int ni = 0; ni < 4; ++ni) {
      long gc = colBase + wc * 64 + ni * 16 + fr;
#pragma unroll
      for (int r = 0; r < 4; ++r) {
        float v = acc[mi][ni][r];
        if (OUT_BF16) {
          ((unsigned short*)C)[(gr + r) * (long)N + gc] = f2b(v);
        } else {
          ((float*)C)[(gr + r) * (long)N + gc] = v + bias[gc];
        }
      }
    }
  }
}

// ---------------- gather top-k keys: Kg[b][j][c] (zero-padded to 416) -------
__global__ __launch_bounds__(256) void gather_k(const unsigned short* __restrict__ QKV,
                                                const int* __restrict__ sel,
                                                unsigned short* __restrict__ Kg) {
  int j = blockIdx.x;           // 0..415
  int b = blockIdx.y;
  int tid = threadIdx.x;
  if (tid >= 192) return;       // 192 * 8B = 1536B = 768 bf16
  uint2* dst = (uint2*)(Kg + ((long)b * KPAD + j) * DD);
  if (j < KSEL) {
    const uint2* src = (const uint2*)(QKV + ((long)b * SS + sel[b * KSEL + j]) * 4608 + 768);
    dst[tid] = src[tid];
  } else {
    dst[tid] = uint2{0u, 0u};
  }
}

// ---------------- gather top-k values transposed: Vt[b][c][j] ---------------
__global__ __launch_bounds__(256) void gather_vt(const unsigned short* __restrict__ QKV,
                                                 const int* __restrict__ sel,
                                                 unsigned short* __restrict__ Vt) {
  __shared__ unsigned short tile[16][68];
  int jt = blockIdx.x, ct = blockIdx.y, b = blockIdx.z;   // 26, 12, 2
  int tid = threadIdx.x;
  int jj = tid & 15, cl = tid >> 4;                        // cl 0..15, 4 c each
  int j = jt * 16 + jj;
  if (j < KSEL) {
    const unsigned short* src = QKV + ((long)b * SS + sel[b * KSEL + j]) * 4608 + 1536 + ct * 64;
    *(uint2*)&tile[jj][cl * 4] = *(const uint2*)&src[cl * 4];
  } else {
    *(uint2*)&tile[jj][cl * 4] = uint2{0u, 0u};
  }
  __syncthreads();
  int c = tid >> 2;             // 0..63
  int jl = (tid & 3) * 4;       // 0,4,8,12
  unsigned v0 = tile[jl + 0][c], v1 = tile[jl + 1][c];
  unsigned v2 = tile[jl + 2][c], v3 = tile[jl + 3][c];
  unsigned short* dst = Vt + ((long)b * DD + ct * 64 + c) * KPAD + jt * 16 + jl;
  *(uint2*)dst = uint2{v0 | (v1 << 16), v2 | (v3 << 16)};
}

// ---------------- global-branch MFMA attention ------------------------------
// Swapped QK^T (S^T = mfma(K,Q)). Fragment layout: lane (fr=lane&15, g=lane>>4)
// holds S^T rows (keys) kt*16+g*4+{0..3} for column q=fr — i.e. 104/416 scores.
// Softmax max/sum therefore needs a cross-lane reduce over lanes sharing fr
// (xor 16 and 32). P^T -> per-wave LDS -> B-frags for PV (O^T).
__global__ __launch_bounds__(256) void attn_global_mfma(
    const unsigned short* __restrict__ QKV,   // QKVx: q at col 0, ld 4608
    const unsigned short* __restrict__ Kg,    // [b][416][768]
    const unsigned short* __restrict__ Vt,    // [b][768][416]
    float* __restrict__ Outp) {               // [b*2048+q][768]
  __shared__ unsigned short P_lds[4][16 * PSTR];
  int tid = threadIdx.x, w = tid >> 6, lane = tid & 63;
  int fr = lane & 15, g = lane >> 4;
  int b = blockIdx.y / HH, h = blockIdx.y % HH;
  int hoff = h * 64;
  int qbase = blockIdx.x * 64 + w * 16;
  long qrow = (long)b * SS + qbase + fr;

  const unsigned short* qptr = QKV + qrow * 4608 + hoff + g * 8;
  bf16x8 bq0 = *(const bf16x8*)(qptr);
  bf16x8 bq1 = *(const bf16x8*)(qptr + 32);

  // S^T fragments: rows = keys (26 tiles of 16), cols = 16 q's
  f32x4 st[26];
  const unsigned short* kbase = Kg + ((long)b * KPAD + fr) * DD + hoff + g * 8;
#pragma unroll
  for (int kt = 0; kt < 26; ++kt) {
    const unsigned short* kp = kbase + (long)kt * 16 * DD;
    bf16x8 a0 = *(const bf16x8*)(kp);
    bf16x8 a1 = *(const bf16x8*)(kp + 32);
    f32x4 z = {0.f, 0.f, 0.f, 0.f};
    z = __builtin_amdgcn_mfma_f32_16x16x32_bf16(a0, bq0, z, 0, 0, 0);
    st[kt] = __builtin_amdgcn_mfma_f32_16x16x32_bf16(a1, bq1, z, 0, 0, 0);
  }

  // softmax over k = kt*16 + g*4 + r; this lane holds 104 of 416 scores of q=fr
  float m = -3.0e38f;
#pragma unroll
  for (int kt = 0; kt < 26; ++kt)
#pragma unroll
    for (int r = 0; r < 4; ++r) {
      int k = kt * 16 + g * 4 + r;
      float s = (k < KSEL) ? st[kt][r] * 0.125f : -1.0e30f;
      st[kt][r] = s;
      m = fmaxf(m, s);
    }
  // reduce max across the 4 lanes sharing fr (lane bits 4,5)
  m = fmaxf(m, __shfl_xor(m, 16, 64));
  m = fmaxf(m, __shfl_xor(m, 32, 64));

  float lsum = 0.f;
#pragma unroll
  for (int kt = 0; kt < 26; ++kt)
#pragma unroll
    for (int r = 0; r < 4; ++r) {
      float e = __expf(st[kt][r] - m);
      st[kt][r] = e;
      lsum += e;
    }
  // reduce sum across the 4 lanes sharing fr
  lsum += __shfl_xor(lsum, 16, 64);
  lsum += __shfl_xor(lsum, 32, 64);

  // write P^T (bf16) to per-wave LDS: row q=fr, col k
  unsigned short* pl = &P_lds[w][fr * PSTR + g * 4];
#pragma unroll
  for (int kt = 0; kt < 26; ++kt) {
    uint2 pk;
    pk.x = (unsigned)f2b(st[kt][0]) | ((unsigned)f2b(st[kt][1]) << 16);
    pk.y = (unsigned)f2b(st[kt][2]) | ((unsigned)f2b(st[kt][3]) << 16);
    *(uint2*)(pl + kt * 16) = pk;
  }

  // PV: O^T[d][q] = sum_k Vt[d][k] * P[q][k]
  f32x4 oacc[4];
#pragma unroll
  for (int mf = 0; mf < 4; ++mf)
#pragma unroll
    for (int r = 0; r < 4; ++r) oacc[mf][r] = 0.f;

  const unsigned short* vb = Vt + ((long)b * DD + hoff + fr) * KPAD + g * 8;
  const unsigned short* pr = &P_lds[w][fr * PSTR + g * 8];
#pragma unroll
  for (int ks = 0; ks < 13; ++ks) {
    bf16x8 pf = *(const bf16x8*)(pr + ks * 32);
#pragma unroll
    for (int mf = 0; mf < 4; ++mf) {
      bf16x8 vf = *(const bf16x8*)(vb + (long)mf * 16 * KPAD + ks * 32);
      oacc[mf] = __builtin_amdgcn_mfma_f32_16x16x32_bf16(vf, pf, oacc[mf], 0, 0, 0);
    }
  }

  float inv = 1.f / lsum;
  float* orow = Outp + qrow * DD + hoff;
#pragma unroll
  for (int mf = 0; mf < 4; ++mf) {
    f32x4 ov;
#pragma unroll
    for (int r = 0; r < 4; ++r) ov[r] = oacc[mf][r] * inv;
    *(f32x4*)(orow + mf * 16 + g * 4) = ov;
  }
}

// ---------------- masked attention (local / temporal), one wave per query ---
template <int MODE>
__global__ __launch_bounds__(256) void attn_kernel(const unsigned short* __restrict__ QKV,
                                                   int ld, int qo, int ko, int vo,
                                                   const int* __restrict__ sel,
                                                   float* __restrict__ Outp) {
  int slot = blockIdx.x * 4 + (threadIdx.x >> 6);
  int lane = threadIdx.x & 63;
  int b = slot / (HH * SS);
  int rem = slot - b * (HH * SS);
  int h = rem / SS;
  int q = rem - h * SS;
  long rowq = (long)b * SS + q;
  int hoff = h * 64;
  float qv = b2f(QKV[rowq * ld + qo + hoff + lane]);
  float m = -3.4e38f, lsum = 0.f, o = 0.f;

  auto body = [&](int j) {
    long rk = (long)b * SS + j;
    float p = qv * b2f(QKV[rk * ld + ko + hoff + lane]);
    p += __shfl_xor(p, 1, 64);
    p += __shfl_xor(p, 2, 64);
    p += __shfl_xor(p, 4, 64);
    p += __shfl_xor(p, 8, 64);
    p += __shfl_xor(p, 16, 64);
    p += __shfl_xor(p, 32, 64);
    float s = p * 0.125f;                       // / sqrt(64)
    float vv = b2f(QKV[rk * ld + vo + hoff + lane]);
    if (s > m) {                                 // wave-uniform
      float cc = __expf(m - s);
      lsum *= cc; o *= cc; m = s;
    }
    float e = __expf(s - m);
    lsum += e; o += e * vv;
  };

  if (MODE == 0) {
    int j0 = q - 8; if (j0 < 0) j0 = 0;
    int j1 = q + 8; if (j1 > SS - 1) j1 = SS - 1;
    for (int j = j0; j <= j1; ++j) body(j);
  } else {
#pragma unroll
    for (int t = 0; t < 8; ++t) body(t * 256);
  }
  Outp[rowq * DD + hoff + lane] = o / lsum;
}

// ---------------- layernorm + gate scale + concat to bf16 -------------------
__global__ __launch_bounds__(256) void ln_gate_concat(
    const float* __restrict__ gsrc, const float* __restrict__ lsrc, const float* __restrict__ tsrc,
    const float* __restrict__ gg, const float* __restrict__ gb,
    const float* __restrict__ lgam, const float* __restrict__ lbet,
    const float* __restrict__ tg, const float* __restrict__ tb,
    const float* __restrict__ fw, unsigned short* __restrict__ comb) {
  int row = blockIdx.x;
  int b = row >> 11;
  int tid = threadIdx.x;
  __shared__ float red[8];
  const float* srcs[3] = {gsrc, lsrc, tsrc};
  const float* gams[3] = {gg, lgam, tg};
  const float* bets[3] = {gb, lbet, tb};
#pragma unroll
  for (int br = 0; br < 3; ++br) {
    const float* src = srcs[br] + (long)row * DD;
    float x0 = src[tid], x1 = src[tid + 256], x2 = src[tid + 512];
    float s = x0 + x1 + x2;
    float ss = x0 * x0 + x1 * x1 + x2 * x2;
#pragma unroll
    for (int msk = 1; msk < 64; msk <<= 1) {
      s += __shfl_xor(s, msk, 64);
      ss += __shfl_xor(ss, msk, 64);
    }
    int wv = tid >> 6, lane = tid & 63;
    if (lane == 0) { red[wv] = s; red[4 + wv] = ss; }
    __syncthreads();
    float S4 = red[0] + red[1] + red[2] + red[3];
    float SQ = red[4] + red[5] + red[6] + red[7];
    float mean = S4 * (1.f / (float)DD);
    float var = SQ * (1.f / (float)DD) - mean * mean;
    float rs = rsqrtf(var + 1e-5f);
    float gate = fw[b * 3 + br];
    const float* gam = gams[br];
    const float* bet = bets[br];
    unsigned short* dst = comb + (long)row * 2304 + br * DD;
    dst[tid]       = f2b(((x0 - mean) * rs * gam[tid]       + bet[tid])       * gate);
    dst[tid + 256] = f2b(((x1 - mean) * rs * gam[tid + 256] + bet[tid + 256]) * gate);
    dst[tid + 512] = f2b(((x2 - mean) * rs * gam[tid + 512] + bet[tid + 512]) * gate);
    __syncthreads();
  }
}

// ---------------- launcher ---------------------------------------------------
extern "C" void kernel_launch(void* const* d_in, const int* in_sizes, int n_in,
                              void* d_out, int out_size, void* d_ws, size_t ws_size,
                              hipStream_t stream) {
  const float* x        = (const float*)d_in[0];
  const float* wgq      = (const float*)d_in[1];
  const float* wgk      = (const float*)d_in[2];
  const float* wgv      = (const float*)d_in[3];
  const float* wlq      = (const float*)d_in[4];
  const float* wlk      = (const float*)d_in[5];
  const float* wlv      = (const float*)d_in[6];
  const float* wtq      = (const float*)d_in[7];
  const float* wtk      = (const float*)d_in[8];
  const float* wtv      = (const float*)d_in[9];
  const float* w_out    = (const float*)d_in[10];
  const float* b_out    = (const float*)d_in[11];
  const float* w_gate   = (const float*)d_in[12];
  const float* b_gate   = (const float*)d_in[13];
  const float* w_sparse = (const float*)d_in[14];
  const float* b_sparse = (const float*)d_in[15];
  const float* g_gamma  = (const float*)d_in[16];
  const float* g_beta   = (const float*)d_in[17];
  const float* l_gamma  = (const float*)d_in[18];
  const float* l_beta   = (const float*)d_in[19];
  const float* t_gamma  = (const float*)d_in[20];
  const float* t_beta   = (const float*)d_in[21];
  float* outp = (float*)d_out;

  unsigned short* xb   = (unsigned short*)d_ws;
  unsigned short* xpb  = xb  + (long)NTOK * DD;
  unsigned short* WTx  = xpb + (long)NTOK * DD;
  unsigned short* WTt  = WTx + (long)4608 * DD;
  unsigned short* WTo  = WTt + (long)2304 * DD;
  unsigned short* QKVx = WTo + (long)DD * 2304;
  unsigned short* QKVt = QKVx + (long)NTOK * 4608;
  unsigned short* comb = QKVt + (long)NTOK * 2304;
  float* gout    = (float*)(comb + (long)NTOK * 2304);
  float* lout    = gout + (long)NTOK * DD;
  float* tout    = lout + (long)NTOK * DD;
  float* imp     = tout + (long)NTOK * DD;
  float* partial = imp + NTOK;
  float* fw      = partial + 32 * DD;
  int*   sel     = (int*)(fw + 8);
  unsigned short* Kg = (unsigned short*)(sel + 832);     // [2][416][768]
  unsigned short* Vt = Kg + (long)BB * KPAD * DD;        // [2][768][416]

  prep_x<<<NTOK * DD / 256, 256, 0, stream>>>(x, xb, xpb);
  transpose_all<<<dim3(24, 72, 10), dim3(32, 8), 0, stream>>>(
      wgq, wgk, wgv, wlq, wlk, wlv, wtq, wtk, wtv, w_out, WTx, WTt, WTo);
  imp_kernel<<<NTOK / 4, 256, 0, stream>>>(x, w_sparse, b_sparse, imp);
  topk_kernel<<<BB, 1024, 0, stream>>>(imp, sel);
  gate1<<<dim3(16, BB), 256, 0, stream>>>(x, partial);
  gate2<<<BB, 256, 0, stream>>>(partial, w_gate, b_gate, fw);

  gemm_tile<1><<<dim3(36, 32), 256, 0, stream>>>(xb,  WTx, QKVx, nullptr, 4608, DD);
  gemm_tile<1><<<dim3(18, 32), 256, 0, stream>>>(xpb, WTt, QKVt, nullptr, 2304, DD);

  gather_k<<<dim3(KPAD, BB), 256, 0, stream>>>(QKVx, sel, Kg);
  gather_vt<<<dim3(26, 12, BB), 256, 0, stream>>>(QKVx, sel, Vt);
  attn_global_mfma<<<dim3(32, BB * HH), 256, 0, stream>>>(QKVx, Kg, Vt, gout);

  attn_kernel<0><<<NTOK * HH / 4, 256, 0, stream>>>(QKVx, 4608, 2304, 3072, 3840, nullptr, lout);
  attn_kernel<1><<<NTOK * HH / 4, 256, 0, stream>>>(QKVt, 2304, 0,    768,  1536, nullptr, tout);

  ln_gate_concat<<<NTOK, 256, 0, stream>>>(gout, lout, tout, g_gamma, g_beta,
                                           l_gamma, l_beta, t_gamma, t_beta, fw, comb);
  gemm_tile<0><<<dim3(6, 32), 256, 0, stream>>>(comb, WTo, outp, b_out, 768, 2304);
}

// Round 5
// 316.794 us; speedup vs baseline: 6.1401x; 1.2238x over previous
//
#include <hip/hip_runtime.h>
#include <cstdint>

// Problem constants
constexpr int BB   = 2;
constexpr int SS   = 2048;
constexpr int DD   = 768;
constexpr int HH   = 12;
constexpr int NTOK = BB * SS;          // 4096
constexpr int KSEL = 409;              // int((1-0.8)*2048)
constexpr int KPAD = 416;              // 26*16
constexpr int PSTR = 424;              // global P_lds stride

typedef __bf16 bf16x8 __attribute__((ext_vector_type(8)));
typedef float  f32x4  __attribute__((ext_vector_type(4)));

__device__ __forceinline__ float b2f(unsigned short u) {
  return __uint_as_float(((unsigned)u) << 16);
}
__device__ __forceinline__ unsigned short f2b(float f) {
  unsigned u = __float_as_uint(f);
  u += 0x7fffu + ((u >> 16) & 1u);   // RNE
  return (unsigned short)(u >> 16);
}

__device__ __forceinline__ void gload_lds16(const void* gsrc, void* ldst) {
  __builtin_amdgcn_global_load_lds(
      (__attribute__((address_space(1))) void*)(gsrc),
      (__attribute__((address_space(3))) void*)(ldst), 16, 0, 0);
}

// ---------------- prep: xb = bf16(x); xpb = bf16(x + pos_encoding) ----------
__global__ __launch_bounds__(256) void prep_x(const float* __restrict__ x,
                                              unsigned short* __restrict__ xb,
                                              unsigned short* __restrict__ xpb) {
  long i = (long)blockIdx.x * 256 + threadIdx.x;      // over NTOK*DD
  float xv = x[i];
  int c = (int)(i % DD);
  int srow = (int)((i / DD) & (SS - 1));
  xb[i] = f2b(xv);
  int j2 = c & ~1;
  float freq = __expf((float)j2 * -0.011992630692677323f);  // exp(-j2*ln(1e4)/768)
  float ang = (float)srow * freq;
  float pe = (c & 1) ? cosf(ang) : sinf(ang);
  xpb[i] = f2b(xv + pe);
}

// ---------------- transpose all weights to bf16 B^T (N x K) -----------------
__global__ void transpose_all(const float* w0, const float* w1, const float* w2,
                              const float* w3, const float* w4, const float* w5,
                              const float* w6, const float* w7, const float* w8,
                              const float* w9,
                              unsigned short* WTx, unsigned short* WTt,
                              unsigned short* WTo) {
  __shared__ float tile[32][33];
  int z = blockIdx.z;
  const float* src;
  unsigned short* dst;
  int R;
  if (z < 6)      { const float* a[6] = {w0,w1,w2,w3,w4,w5}; src = a[z];   dst = WTx + (long)z*DD*DD;     R = DD;   }
  else if (z < 9) { const float* a[3] = {w6,w7,w8};          src = a[z-6]; dst = WTt + (long)(z-6)*DD*DD; R = DD;   }
  else            { src = w9; dst = WTo; R = 2304; }
  int r0 = blockIdx.y * 32;
  if (r0 >= R) return;
  int c0 = blockIdx.x * 32;
  int tx = threadIdx.x, ty = threadIdx.y;
  for (int i = ty; i < 32; i += 8) tile[i][tx] = src[(long)(r0 + i) * DD + c0 + tx];
  __syncthreads();
  for (int i = ty; i < 32; i += 8) dst[(long)(c0 + i) * R + r0 + tx] = f2b(tile[tx][i]);
}

// ---------------- importance = x @ w_sparse + b ------------------------------
__global__ __launch_bounds__(256) void imp_kernel(const float* __restrict__ x,
                                                  const float* __restrict__ wsp,
                                                  const float* __restrict__ bsp,
                                                  float* __restrict__ imp) {
  int row = blockIdx.x * 4 + (threadIdx.x >> 6);
  int lane = threadIdx.x & 63;
  const float* xp = x + (long)row * DD;
  float acc = 0.f;
  for (int d = lane; d < DD; d += 64) acc += xp[d] * wsp[d];
#pragma unroll
  for (int m = 1; m < 64; m <<= 1) acc += __shfl_xor(acc, m, 64);
  if (lane == 0) imp[row] = acc + bsp[0];
}

// ---------------- top-k via bitonic sort (value desc, index asc) ------------
__global__ __launch_bounds__(1024) void topk_kernel(const float* __restrict__ imp,
                                                    int* __restrict__ sel) {
  __shared__ unsigned long long keys[SS];
  int b = blockIdx.x, tid = threadIdx.x;
  for (int i = tid; i < SS; i += 1024) {
    float v = imp[b * SS + i];
    unsigned u = __float_as_uint(v);
    u = (u & 0x80000000u) ? ~u : (u | 0x80000000u);   // ascending-order map
    unsigned du = ~u;                                  // descending
    keys[i] = ((unsigned long long)du << 32) | (unsigned)i;
  }
  __syncthreads();
  for (int k = 2; k <= SS; k <<= 1) {
    for (int j = k >> 1; j > 0; j >>= 1) {
      for (int i = tid; i < SS; i += 1024) {
        int p = i ^ j;
        if (p > i) {
          unsigned long long a = keys[i], bb = keys[p];
          bool up = ((i & k) == 0);
          if ((a > bb) == up) { keys[i] = bb; keys[p] = a; }
        }
      }
      __syncthreads();
    }
  }
  for (int i = tid; i < KSEL; i += 1024) sel[b * KSEL + i] = (int)(keys[i] & 0xffffffffu);
}

// ---------------- gate: mean over s, then softmax(mean @ w_gate + b) --------
__global__ __launch_bounds__(256) void gate1(const float* __restrict__ x,
                                             float* __restrict__ partial) {
  int b = blockIdx.y, chunk = blockIdx.x, tid = threadIdx.x;
  for (int c = tid; c < DD; c += 256) {
    const float* xp = x + ((long)(b * SS + chunk * 128)) * DD + c;
    float acc = 0.f;
    for (int s2 = 0; s2 < 128; ++s2) acc += xp[(long)s2 * DD];
    partial[(long)(b * 16 + chunk) * DD + c] = acc;
  }
}

__global__ __launch_bounds__(256) void gate2(const float* __restrict__ partial,
                                             const float* __restrict__ w_gate,
                                             const float* __restrict__ b_gate,
                                             float* __restrict__ fw) {
  int b = blockIdx.x, tid = threadIdx.x;
  __shared__ float meanbuf[DD];
  __shared__ float lg[3];
  for (int c = tid; c < DD; c += 256) {
    float acc = 0.f;
    for (int p = 0; p < 16; ++p) acc += partial[(long)(b * 16 + p) * DD + c];
    meanbuf[c] = acc * (1.0f / (float)SS);
  }
  __syncthreads();
  if (tid < 3) {
    float acc = b_gate[tid];
    for (int d = 0; d < DD; ++d) acc += meanbuf[d] * w_gate[d * 3 + tid];
    lg[tid] = acc;
  }
  __syncthreads();
  if (tid == 0) {
    float mx = fmaxf(lg[0], fmaxf(lg[1], lg[2]));
    float e0 = expf(lg[0] - mx), e1 = expf(lg[1] - mx), e2 = expf(lg[2] - mx);
    float inv = 1.f / (e0 + e1 + e2);
    fw[b * 3 + 0] = e0 * inv; fw[b * 3 + 1] = e1 * inv; fw[b * 3 + 2] = e2 * inv;
  }
}

// ---------------- MFMA GEMM: C = A(MxK) * BT(NxK)^T --------------------------
template <int OUT_BF16>
__global__ __launch_bounds__(256) void gemm_tile(const unsigned short* __restrict__ A,
                                                 const unsigned short* __restrict__ BT,
                                                 void* __restrict__ C,
                                                 const float* __restrict__ bias,
                                                 int N, int K) {
  __shared__ unsigned short As[128 * 32];
  __shared__ unsigned short Bs[128 * 32];
  const int tid = threadIdx.x;
  const int lane = tid & 63;
  const int wv = tid >> 6;
  const int wr = wv >> 1, wc = wv & 1;
  const long rowBase = (long)blockIdx.y * 128;
  const long colBase = (long)blockIdx.x * 128;

  f32x4 acc[4][4];
#pragma unroll
  for (int i = 0; i < 4; ++i)
#pragma unroll
    for (int j = 0; j < 4; ++j)
#pragma unroll
      for (int r = 0; r < 4; ++r) acc[i][j][r] = 0.f;

  const int g0 = tid, g1 = tid + 256;
  const int r0 = g0 >> 2, k80 = (g0 & 3) ^ ((r0 >> 1) & 3);
  const int r1 = g1 >> 2, k81 = (g1 & 3) ^ ((r1 >> 1) & 3);
  const unsigned short* ga0 = A + (rowBase + r0) * (long)K + k80 * 8;
  const unsigned short* ga1 = A + (rowBase + r1) * (long)K + k81 * 8;
  const unsigned short* gb0 = BT + (colBase + r0) * (long)K + k80 * 8;
  const unsigned short* gb1 = BT + (colBase + r1) * (long)K + k81 * 8;
  unsigned short* la0 = As + g0 * 8;
  unsigned short* la1 = As + g1 * 8;
  unsigned short* lb0 = Bs + g0 * 8;
  unsigned short* lb1 = Bs + g1 * 8;

  const int k8 = lane >> 4;
  const int fr = lane & 15;
  int aoff[4], boff[4];
#pragma unroll
  for (int i = 0; i < 4; ++i) {
    int rowA = wr * 64 + i * 16 + fr;
    aoff[i] = (rowA * 4 + (k8 ^ ((rowA >> 1) & 3))) * 8;
    int rowB = wc * 64 + i * 16 + fr;
    boff[i] = (rowB * 4 + (k8 ^ ((rowB >> 1) & 3))) * 8;
  }

  for (int kt = 0; kt < K; kt += 32) {
    gload_lds16(ga0 + kt, la0);
    gload_lds16(ga1 + kt, la1);
    gload_lds16(gb0 + kt, lb0);
    gload_lds16(gb1 + kt, lb1);
    __syncthreads();
    bf16x8 af[4], bfr[4];
#pragma unroll
    for (int i = 0; i < 4; ++i) af[i] = *(const bf16x8*)(As + aoff[i]);
#pragma unroll
    for (int i = 0; i < 4; ++i) bfr[i] = *(const bf16x8*)(Bs + boff[i]);
#pragma unroll
    for (int mi = 0; mi < 4; ++mi)
#pragma unroll
      for (int ni = 0; ni < 4; ++ni)
        acc[mi][ni] = __builtin_amdgcn_mfma_f32_16x16x32_bf16(af[mi], bfr[ni], acc[mi][ni], 0, 0, 0);
    __syncthreads();
  }

  const int orow0 = (lane >> 4) * 4;
#pragma unroll
  for (int mi = 0; mi < 4; ++mi) {
    long gr = rowBase + wr * 64 + mi * 16 + orow0;
#pragma unroll
    for (int ni = 0; ni < 4; ++ni) {
      long gc = colBase + wc * 64 + ni * 16 + fr;
#pragma unroll
      for (int r = 0; r < 4; ++r) {
        float v = acc[mi][ni][r];
        if (OUT_BF16) {
          ((unsigned short*)C)[(gr + r) * (long)N + gc] = f2b(v);
        } else {
          ((float*)C)[(gr + r) * (long)N + gc] = v + bias[gc];
        }
      }
    }
  }
}

// ---------------- gather top-k keys: Kg[b][j][c] (zero-padded to 416) -------
__global__ __launch_bounds__(256) void gather_k(const unsigned short* __restrict__ QKV,
                                                const int* __restrict__ sel,
                                                unsigned short* __restrict__ Kg) {
  int j = blockIdx.x;           // 0..415
  int b = blockIdx.y;
  int tid = threadIdx.x;
  if (tid >= 192) return;       // 192 * 8B = 1536B = 768 bf16
  uint2* dst = (uint2*)(Kg + ((long)b * KPAD + j) * DD);
  if (j < KSEL) {
    const uint2* src = (const uint2*)(QKV + ((long)b * SS + sel[b * KSEL + j]) * 4608 + 768);
    dst[tid] = src[tid];
  } else {
    dst[tid] = uint2{0u, 0u};
  }
}

// ---------------- gather top-k values transposed: Vt[b][c][j] ---------------
__global__ __launch_bounds__(256) void gather_vt(const unsigned short* __restrict__ QKV,
                                                 const int* __restrict__ sel,
                                                 unsigned short* __restrict__ Vt) {
  __shared__ unsigned short tile[16][68];
  int jt = blockIdx.x, ct = blockIdx.y, b = blockIdx.z;   // 26, 12, 2
  int tid = threadIdx.x;
  int jj = tid & 15, cl = tid >> 4;                        // cl 0..15, 4 c each
  int j = jt * 16 + jj;
  if (j < KSEL) {
    const unsigned short* src = QKV + ((long)b * SS + sel[b * KSEL + j]) * 4608 + 1536 + ct * 64;
    *(uint2*)&tile[jj][cl * 4] = *(const uint2*)&src[cl * 4];
  } else {
    *(uint2*)&tile[jj][cl * 4] = uint2{0u, 0u};
  }
  __syncthreads();
  int c = tid >> 2;             // 0..63
  int jl = (tid & 3) * 4;       // 0,4,8,12
  unsigned v0 = tile[jl + 0][c], v1 = tile[jl + 1][c];
  unsigned v2 = tile[jl + 2][c], v3 = tile[jl + 3][c];
  unsigned short* dst = Vt + ((long)b * DD + ct * 64 + c) * KPAD + jt * 16 + jl;
  *(uint2*)dst = uint2{v0 | (v1 << 16), v2 | (v3 << 16)};
}

// ---------------- full V transpose for local branch: Vtl[b][c][s] -----------
__global__ __launch_bounds__(256) void transpose_vl(const unsigned short* __restrict__ QKV,
                                                    unsigned short* __restrict__ Vtl) {
  __shared__ unsigned short tile[16][68];
  int jt = blockIdx.x, ct = blockIdx.y, b = blockIdx.z;   // 128, 12, 2
  int tid = threadIdx.x;
  int jj = tid & 15, cl = tid >> 4;
  const unsigned short* src = QKV + ((long)b * SS + jt * 16 + jj) * 4608 + 3840 + ct * 64;
  *(uint2*)&tile[jj][cl * 4] = *(const uint2*)&src[cl * 4];
  __syncthreads();
  int c = tid >> 2;
  int jl = (tid & 3) * 4;
  unsigned v0 = tile[jl + 0][c], v1 = tile[jl + 1][c];
  unsigned v2 = tile[jl + 2][c], v3 = tile[jl + 3][c];
  unsigned short* dst = Vtl + ((long)b * DD + ct * 64 + c) * (long)SS + jt * 16 + jl;
  *(uint2*)dst = uint2{v0 | (v1 << 16), v2 | (v3 << 16)};
}

// ---------------- temporal gathers: K8[b][16][768], Vt8[b][768][32] ---------
__global__ __launch_bounds__(256) void gather_t8(const unsigned short* __restrict__ QKVt,
                                                 unsigned short* __restrict__ K8,
                                                 unsigned short* __restrict__ Vt8) {
  int b = blockIdx.y;
  int c = blockIdx.x * 256 + threadIdx.x;   // grid.x = 3 -> c in [0,768)
#pragma unroll
  for (int j = 0; j < 8; ++j) {
    const unsigned short* src = QKVt + ((long)b * SS + j * 256) * 2304 + c;
    K8[((long)b * 16 + j) * DD + c]  = src[768];
    Vt8[((long)b * DD + c) * 32 + j] = src[1536];
  }
#pragma unroll
  for (int j = 8; j < 16; ++j) K8[((long)b * 16 + j) * DD + c] = 0;
#pragma unroll
  for (int j = 8; j < 32; ++j) Vt8[((long)b * DD + c) * 32 + j] = 0;
}

// ---------------- global-branch MFMA attention ------------------------------
// Swapped QK^T (S^T = mfma(K,Q)). Lane (fr=lane&15, g=lane>>4) holds S^T rows
// (keys) kt*16+g*4+{0..3} for column q=fr. Softmax max/sum reduce over lanes
// sharing fr (xor 16, 32). P^T -> per-wave LDS -> B-frags for PV (O^T).
__global__ __launch_bounds__(256) void attn_global_mfma(
    const unsigned short* __restrict__ QKV,   // QKVx: q at col 0, ld 4608
    const unsigned short* __restrict__ Kg,    // [b][416][768]
    const unsigned short* __restrict__ Vt,    // [b][768][416]
    float* __restrict__ Outp) {               // [b*2048+q][768]
  __shared__ unsigned short P_lds[4][16 * PSTR];
  int tid = threadIdx.x, w = tid >> 6, lane = tid & 63;
  int fr = lane & 15, g = lane >> 4;
  int b = blockIdx.y / HH, h = blockIdx.y % HH;
  int hoff = h * 64;
  int qbase = blockIdx.x * 64 + w * 16;
  long qrow = (long)b * SS + qbase + fr;

  const unsigned short* qptr = QKV + qrow * 4608 + hoff + g * 8;
  bf16x8 bq0 = *(const bf16x8*)(qptr);
  bf16x8 bq1 = *(const bf16x8*)(qptr + 32);

  f32x4 st[26];
  const unsigned short* kbase = Kg + ((long)b * KPAD + fr) * DD + hoff + g * 8;
#pragma unroll
  for (int kt = 0; kt < 26; ++kt) {
    const unsigned short* kp = kbase + (long)kt * 16 * DD;
    bf16x8 a0 = *(const bf16x8*)(kp);
    bf16x8 a1 = *(const bf16x8*)(kp + 32);
    f32x4 z = {0.f, 0.f, 0.f, 0.f};
    z = __builtin_amdgcn_mfma_f32_16x16x32_bf16(a0, bq0, z, 0, 0, 0);
    st[kt] = __builtin_amdgcn_mfma_f32_16x16x32_bf16(a1, bq1, z, 0, 0, 0);
  }

  float m = -3.0e38f;
#pragma unroll
  for (int kt = 0; kt < 26; ++kt)
#pragma unroll
    for (int r = 0; r < 4; ++r) {
      int k = kt * 16 + g * 4 + r;
      float s = (k < KSEL) ? st[kt][r] * 0.125f : -1.0e30f;
      st[kt][r] = s;
      m = fmaxf(m, s);
    }
  m = fmaxf(m, __shfl_xor(m, 16, 64));
  m = fmaxf(m, __shfl_xor(m, 32, 64));

  float lsum = 0.f;
#pragma unroll
  for (int kt = 0; kt < 26; ++kt)
#pragma unroll
    for (int r = 0; r < 4; ++r) {
      float e = __expf(st[kt][r] - m);
      st[kt][r] = e;
      lsum += e;
    }
  lsum += __shfl_xor(lsum, 16, 64);
  lsum += __shfl_xor(lsum, 32, 64);

  unsigned short* pl = &P_lds[w][fr * PSTR + g * 4];
#pragma unroll
  for (int kt = 0; kt < 26; ++kt) {
    uint2 pk;
    pk.x = (unsigned)f2b(st[kt][0]) | ((unsigned)f2b(st[kt][1]) << 16);
    pk.y = (unsigned)f2b(st[kt][2]) | ((unsigned)f2b(st[kt][3]) << 16);
    *(uint2*)(pl + kt * 16) = pk;
  }

  f32x4 oacc[4];
#pragma unroll
  for (int mf = 0; mf < 4; ++mf)
#pragma unroll
    for (int r = 0; r < 4; ++r) oacc[mf][r] = 0.f;

  const unsigned short* vb = Vt + ((long)b * DD + hoff + fr) * KPAD + g * 8;
  const unsigned short* pr = &P_lds[w][fr * PSTR + g * 8];
#pragma unroll
  for (int ks = 0; ks < 13; ++ks) {
    bf16x8 pf = *(const bf16x8*)(pr + ks * 32);
#pragma unroll
    for (int mf = 0; mf < 4; ++mf) {
      bf16x8 vf = *(const bf16x8*)(vb + (long)mf * 16 * KPAD + ks * 32);
      oacc[mf] = __builtin_amdgcn_mfma_f32_16x16x32_bf16(vf, pf, oacc[mf], 0, 0, 0);
    }
  }

  float inv = 1.f / lsum;
  float* orow = Outp + qrow * DD + hoff;
#pragma unroll
  for (int mf = 0; mf < 4; ++mf) {
    f32x4 ov;
#pragma unroll
    for (int r = 0; r < 4; ++r) ov[r] = oacc[mf][r] * inv;
    *(f32x4*)(orow + mf * 16 + g * 4) = ov;
  }
}

// ---------------- window MFMA attention (local / temporal) ------------------
// MODE 0 (local): 32 contiguous keys kstart..kstart+31 cover all 16 queries'
//   windows; per-lane mask -8 <= j-q <= 8. K read from QKVx, V from Vtl.
// MODE 1 (temporal): keys t*256 gathered into K8 (16 rows, 8 valid) and
//   Vt8 (32 cols, 8 valid); mask idx < 8.
template <int MODE>
__global__ __launch_bounds__(256) void attn_win_mfma(
    const unsigned short* __restrict__ QKV,   // MODE0: QKVx ld4608; MODE1: QKVt ld2304
    const unsigned short* __restrict__ K8,    // MODE1 only: [b][16][768]
    const unsigned short* __restrict__ Vt,    // MODE0: [b][768][2048]; MODE1: [b][768][32]
    float* __restrict__ Outp) {
  constexpr int LD   = (MODE == 0) ? 4608 : 2304;
  constexpr int QO   = (MODE == 0) ? 2304 : 0;
  constexpr int KO   = 3072;
  constexpr long VSTR = (MODE == 0) ? SS : 32;
  __shared__ unsigned short P_lds[4][16 * 40];
  int tid = threadIdx.x, w = tid >> 6, lane = tid & 63;
  int fr = lane & 15, g = lane >> 4;
  int b = blockIdx.y / HH, h = blockIdx.y % HH, hoff = h * 64;
  int qbase = blockIdx.x * 64 + w * 16;
  long qrow = (long)b * SS + qbase + fr;

  const unsigned short* qptr = QKV + qrow * LD + QO + hoff + g * 8;
  bf16x8 bq0 = *(const bf16x8*)(qptr);
  bf16x8 bq1 = *(const bf16x8*)(qptr + 32);

  int kstart = qbase - 8;
  if (kstart < 0) kstart = 0;
  if (kstart > SS - 32) kstart = SS - 32;

  f32x4 st[2];
  if (MODE == 0) {
#pragma unroll
    for (int kt = 0; kt < 2; ++kt) {
      const unsigned short* kp =
          QKV + ((long)b * SS + kstart + kt * 16 + fr) * LD + KO + hoff + g * 8;
      bf16x8 a0 = *(const bf16x8*)(kp);
      bf16x8 a1 = *(const bf16x8*)(kp + 32);
      f32x4 z = {0.f, 0.f, 0.f, 0.f};
      z = __builtin_amdgcn_mfma_f32_16x16x32_bf16(a0, bq0, z, 0, 0, 0);
      st[kt] = __builtin_amdgcn_mfma_f32_16x16x32_bf16(a1, bq1, z, 0, 0, 0);
    }
  } else {
    const unsigned short* kp = K8 + ((long)b * 16 + fr) * DD + hoff + g * 8;
    bf16x8 a0 = *(const bf16x8*)(kp);
    bf16x8 a1 = *(const bf16x8*)(kp + 32);
    f32x4 z = {0.f, 0.f, 0.f, 0.f};
    z = __builtin_amdgcn_mfma_f32_16x16x32_bf16(a0, bq0, z, 0, 0, 0);
    st[0] = __builtin_amdgcn_mfma_f32_16x16x32_bf16(a1, bq1, z, 0, 0, 0);
    st[1] = f32x4{0.f, 0.f, 0.f, 0.f};
  }

  float m = -3.0e38f;
#pragma unroll
  for (int kt = 0; kt < 2; ++kt)
#pragma unroll
    for (int r = 0; r < 4; ++r) {
      int idx = kt * 16 + g * 4 + r;
      bool valid;
      if (MODE == 0) {
        int rel = kstart + idx - qbase - fr;
        valid = (rel >= -8) && (rel <= 8);
      } else {
        valid = (idx < 8);
      }
      float s = valid ? st[kt][r] * 0.125f : -1.0e30f;
      st[kt][r] = s;
      m = fmaxf(m, s);
    }
  m = fmaxf(m, __shfl_xor(m, 16, 64));
  m = fmaxf(m, __shfl_xor(m, 32, 64));

  float lsum = 0.f;
#pragma unroll
  for (int kt = 0; kt < 2; ++kt)
#pragma unroll
    for (int r = 0; r < 4; ++r) {
      float e = __expf(st[kt][r] - m);
      st[kt][r] = e;
      lsum += e;
    }
  lsum += __shfl_xor(lsum, 16, 64);
  lsum += __shfl_xor(lsum, 32, 64);

  unsigned short* pl = &P_lds[w][fr * 40 + g * 4];
#pragma unroll
  for (int kt = 0; kt < 2; ++kt) {
    uint2 pk;
    pk.x = (unsigned)f2b(st[kt][0]) | ((unsigned)f2b(st[kt][1]) << 16);
    pk.y = (unsigned)f2b(st[kt][2]) | ((unsigned)f2b(st[kt][3]) << 16);
    *(uint2*)(pl + kt * 16) = pk;
  }

  f32x4 oacc[4];
#pragma unroll
  for (int mf = 0; mf < 4; ++mf)
#pragma unroll
    for (int r = 0; r < 4; ++r) oacc[mf][r] = 0.f;

  const unsigned short* pr = &P_lds[w][fr * 40 + g * 8];
  bf16x8 pf = *(const bf16x8*)(pr);
  long kb2 = (MODE == 0) ? kstart : 0;
#pragma unroll
  for (int mf = 0; mf < 4; ++mf) {
    const unsigned short* vp =
        Vt + ((long)b * DD + hoff + mf * 16 + fr) * VSTR + kb2 + g * 8;
    bf16x8 vf = *(const bf16x8*)(vp);
    oacc[mf] = __builtin_amdgcn_mfma_f32_16x16x32_bf16(vf, pf, oacc[mf], 0, 0, 0);
  }

  float inv = 1.f / lsum;
  float* orow = Outp + qrow * DD + hoff;
#pragma unroll
  for (int mf = 0; mf < 4; ++mf) {
    f32x4 ov;
#pragma unroll
    for (int r = 0; r < 4; ++r) ov[r] = oacc[mf][r] * inv;
    *(f32x4*)(orow + mf * 16 + g * 4) = ov;
  }
}

// ---------------- layernorm + gate scale + concat to bf16 -------------------
__global__ __launch_bounds__(256) void ln_gate_concat(
    const float* __restrict__ gsrc, const float* __restrict__ lsrc, const float* __restrict__ tsrc,
    const float* __restrict__ gg, const float* __restrict__ gb,
    const float* __restrict__ lgam, const float* __restrict__ lbet,
    const float* __restrict__ tg, const float* __restrict__ tb,
    const float* __restrict__ fw, unsigned short* __restrict__ comb) {
  int row = blockIdx.x;
  int b = row >> 11;
  int tid = threadIdx.x;
  __shared__ float red[8];
  const float* srcs[3] = {gsrc, lsrc, tsrc};
  const float* gams[3] = {gg, lgam, tg};
  const float* bets[3] = {gb, lbet, tb};
#pragma unroll
  for (int br = 0; br < 3; ++br) {
    const float* src = srcs[br] + (long)row * DD;
    float x0 = src[tid], x1 = src[tid + 256], x2 = src[tid + 512];
    float s = x0 + x1 + x2;
    float ss = x0 * x0 + x1 * x1 + x2 * x2;
#pragma unroll
    for (int msk = 1; msk < 64; msk <<= 1) {
      s += __shfl_xor(s, msk, 64);
      ss += __shfl_xor(ss, msk, 64);
    }
    int wv = tid >> 6, lane = tid & 63;
    if (lane == 0) { red[wv] = s; red[4 + wv] = ss; }
    __syncthreads();
    float S4 = red[0] + red[1] + red[2] + red[3];
    float SQ = red[4] + red[5] + red[6] + red[7];
    float mean = S4 * (1.f / (float)DD);
    float var = SQ * (1.f / (float)DD) - mean * mean;
    float rs = rsqrtf(var + 1e-5f);
    float gate = fw[b * 3 + br];
    const float* gam = gams[br];
    const float* bet = bets[br];
    unsigned short* dst = comb + (long)row * 2304 + br * DD;
    dst[tid]       = f2b(((x0 - mean) * rs * gam[tid]       + bet[tid])       * gate);
    dst[tid + 256] = f2b(((x1 - mean) * rs * gam[tid + 256] + bet[tid + 256]) * gate);
    dst[tid + 512] = f2b(((x2 - mean) * rs * gam[tid + 512] + bet[tid + 512]) * gate);
    __syncthreads();
  }
}

// ---------------- launcher ---------------------------------------------------
extern "C" void kernel_launch(void* const* d_in, const int* in_sizes, int n_in,
                              void* d_out, int out_size, void* d_ws, size_t ws_size,
                              hipStream_t stream) {
  const float* x        = (const float*)d_in[0];
  const float* wgq      = (const float*)d_in[1];
  const float* wgk      = (const float*)d_in[2];
  const float* wgv      = (const float*)d_in[3];
  const float* wlq      = (const float*)d_in[4];
  const float* wlk      = (const float*)d_in[5];
  const float* wlv      = (const float*)d_in[6];
  const float* wtq      = (const float*)d_in[7];
  const float* wtk      = (const float*)d_in[8];
  const float* wtv      = (const float*)d_in[9];
  const float* w_out    = (const float*)d_in[10];
  const float* b_out    = (const float*)d_in[11];
  const float* w_gate   = (const float*)d_in[12];
  const float* b_gate   = (const float*)d_in[13];
  const float* w_sparse = (const float*)d_in[14];
  const float* b_sparse = (const float*)d_in[15];
  const float* g_gamma  = (const float*)d_in[16];
  const float* g_beta   = (const float*)d_in[17];
  const float* l_gamma  = (const float*)d_in[18];
  const float* l_beta   = (const float*)d_in[19];
  const float* t_gamma  = (const float*)d_in[20];
  const float* t_beta   = (const float*)d_in[21];
  float* outp = (float*)d_out;

  unsigned short* xb   = (unsigned short*)d_ws;
  unsigned short* xpb  = xb  + (long)NTOK * DD;
  unsigned short* WTx  = xpb + (long)NTOK * DD;
  unsigned short* WTt  = WTx + (long)4608 * DD;
  unsigned short* WTo  = WTt + (long)2304 * DD;
  unsigned short* QKVx = WTo + (long)DD * 2304;
  unsigned short* QKVt = QKVx + (long)NTOK * 4608;
  unsigned short* comb = QKVt + (long)NTOK * 2304;
  float* gout    = (float*)(comb + (long)NTOK * 2304);
  float* lout    = gout + (long)NTOK * DD;
  float* tout    = lout + (long)NTOK * DD;
  float* imp     = tout + (long)NTOK * DD;
  float* partial = imp + NTOK;
  float* fw      = partial + 32 * DD;
  int*   sel     = (int*)(fw + 8);
  unsigned short* Kg = (unsigned short*)(sel + 832);     // [2][416][768]
  unsigned short* Vt = Kg + (long)BB * KPAD * DD;        // [2][768][416]
  // buffer reuse (stream-ordered; xb/xpb dead after the projection GEMMs):
  unsigned short* Vtl = xpb;                             // [2][768][2048] (same size as xpb)
  unsigned short* K8  = xb;                              // [2][16][768]
  unsigned short* Vt8 = xb + (long)BB * 16 * DD;         // [2][768][32]

  prep_x<<<NTOK * DD / 256, 256, 0, stream>>>(x, xb, xpb);
  transpose_all<<<dim3(24, 72, 10), dim3(32, 8), 0, stream>>>(
      wgq, wgk, wgv, wlq, wlk, wlv, wtq, wtk, wtv, w_out, WTx, WTt, WTo);
  imp_kernel<<<NTOK / 4, 256, 0, stream>>>(x, w_sparse, b_sparse, imp);
  topk_kernel<<<BB, 1024, 0, stream>>>(imp, sel);
  gate1<<<dim3(16, BB), 256, 0, stream>>>(x, partial);
  gate2<<<BB, 256, 0, stream>>>(partial, w_gate, b_gate, fw);

  gemm_tile<1><<<dim3(36, 32), 256, 0, stream>>>(xb,  WTx, QKVx, nullptr, 4608, DD);
  gemm_tile<1><<<dim3(18, 32), 256, 0, stream>>>(xpb, WTt, QKVt, nullptr, 2304, DD);

  gather_k<<<dim3(KPAD, BB), 256, 0, stream>>>(QKVx, sel, Kg);
  gather_vt<<<dim3(26, 12, BB), 256, 0, stream>>>(QKVx, sel, Vt);
  attn_global_mfma<<<dim3(32, BB * HH), 256, 0, stream>>>(QKVx, Kg, Vt, gout);

  transpose_vl<<<dim3(128, 12, BB), 256, 0, stream>>>(QKVx, Vtl);
  gather_t8<<<dim3(3, BB), 256, 0, stream>>>(QKVt, K8, Vt8);
  attn_win_mfma<0><<<dim3(32, BB * HH), 256, 0, stream>>>(QKVx, nullptr, Vtl, lout);
  attn_win_mfma<1><<<dim3(32, BB * HH), 256, 0, stream>>>(QKVt, K8, Vt8, tout);

  ln_gate_concat<<<NTOK, 256, 0, stream>>>(gout, lout, tout, g_gamma, g_beta,
                                           l_gamma, l_beta, t_gamma, t_beta, fw, comb);
  gemm_tile<0><<<dim3(6, 32), 256, 0, stream>>>(comb, WTo, outp, b_out, 768, 2304);
}

// Round 6
// 280.492 us; speedup vs baseline: 6.9348x; 1.1294x over previous
//
#include <hip/hip_runtime.h>
#include <cstdint>

// Problem constants
constexpr int BB   = 2;
constexpr int SS   = 2048;
constexpr int DD   = 768;
constexpr int HH   = 12;
constexpr int NTOK = BB * SS;          // 4096
constexpr int KSEL = 409;              // int((1-0.8)*2048)
constexpr int KPAD = 448;              // 7 kv-tiles of 64
constexpr int NKT  = 7;                // kv tiles of 64 keys

typedef __bf16 bf16x8 __attribute__((ext_vector_type(8)));
typedef float  f32x4  __attribute__((ext_vector_type(4)));

__device__ __forceinline__ float b2f(unsigned short u) {
  return __uint_as_float(((unsigned)u) << 16);
}
__device__ __forceinline__ unsigned short f2b(float f) {
  unsigned u = __float_as_uint(f);
  u += 0x7fffu + ((u >> 16) & 1u);   // RNE
  return (unsigned short)(u >> 16);
}

__device__ __forceinline__ void gload_lds16(const void* gsrc, void* ldst) {
  __builtin_amdgcn_global_load_lds(
      (__attribute__((address_space(1))) void*)(gsrc),
      (__attribute__((address_space(3))) void*)(ldst), 16, 0, 0);
}

// ---------------- prep: xb = bf16(x); xpb = bf16(x + pos_encoding) ----------
__global__ __launch_bounds__(256) void prep_x(const float* __restrict__ x,
                                              unsigned short* __restrict__ xb,
                                              unsigned short* __restrict__ xpb) {
  long i = (long)blockIdx.x * 256 + threadIdx.x;      // over NTOK*DD
  float xv = x[i];
  int c = (int)(i % DD);
  int srow = (int)((i / DD) & (SS - 1));
  xb[i] = f2b(xv);
  int j2 = c & ~1;
  float freq = __expf((float)j2 * -0.011992630692677323f);  // exp(-j2*ln(1e4)/768)
  float ang = (float)srow * freq;
  float pe = (c & 1) ? cosf(ang) : sinf(ang);
  xpb[i] = f2b(xv + pe);
}

// ---------------- transpose all weights to bf16 B^T (N x K) -----------------
__global__ void transpose_all(const float* w0, const float* w1, const float* w2,
                              const float* w3, const float* w4, const float* w5,
                              const float* w6, const float* w7, const float* w8,
                              const float* w9,
                              unsigned short* WTx, unsigned short* WTt,
                              unsigned short* WTo) {
  __shared__ float tile[32][33];
  int z = blockIdx.z;
  const float* src;
  unsigned short* dst;
  int R;
  if (z < 6)      { const float* a[6] = {w0,w1,w2,w3,w4,w5}; src = a[z];   dst = WTx + (long)z*DD*DD;     R = DD;   }
  else if (z < 9) { const float* a[3] = {w6,w7,w8};          src = a[z-6]; dst = WTt + (long)(z-6)*DD*DD; R = DD;   }
  else            { src = w9; dst = WTo; R = 2304; }
  int r0 = blockIdx.y * 32;
  if (r0 >= R) return;
  int c0 = blockIdx.x * 32;
  int tx = threadIdx.x, ty = threadIdx.y;
  for (int i = ty; i < 32; i += 8) tile[i][tx] = src[(long)(r0 + i) * DD + c0 + tx];
  __syncthreads();
  for (int i = ty; i < 32; i += 8) dst[(long)(c0 + i) * R + r0 + tx] = f2b(tile[tx][i]);
}

// ---------------- importance = x @ w_sparse + b ------------------------------
__global__ __launch_bounds__(256) void imp_kernel(const float* __restrict__ x,
                                                  const float* __restrict__ wsp,
                                                  const float* __restrict__ bsp,
                                                  float* __restrict__ imp) {
  int row = blockIdx.x * 4 + (threadIdx.x >> 6);
  int lane = threadIdx.x & 63;
  const float* xp = x + (long)row * DD;
  float acc = 0.f;
  for (int d = lane; d < DD; d += 64) acc += xp[d] * wsp[d];
#pragma unroll
  for (int m = 1; m < 64; m <<= 1) acc += __shfl_xor(acc, m, 64);
  if (lane == 0) imp[row] = acc + bsp[0];
}

// ---------------- top-k via bitonic sort (value desc, index asc) ------------
__global__ __launch_bounds__(1024) void topk_kernel(const float* __restrict__ imp,
                                                    int* __restrict__ sel) {
  __shared__ unsigned long long keys[SS];
  int b = blockIdx.x, tid = threadIdx.x;
  for (int i = tid; i < SS; i += 1024) {
    float v = imp[b * SS + i];
    unsigned u = __float_as_uint(v);
    u = (u & 0x80000000u) ? ~u : (u | 0x80000000u);   // ascending-order map
    unsigned du = ~u;                                  // descending
    keys[i] = ((unsigned long long)du << 32) | (unsigned)i;
  }
  __syncthreads();
  for (int k = 2; k <= SS; k <<= 1) {
    for (int j = k >> 1; j > 0; j >>= 1) {
      for (int i = tid; i < SS; i += 1024) {
        int p = i ^ j;
        if (p > i) {
          unsigned long long a = keys[i], bb = keys[p];
          bool up = ((i & k) == 0);
          if ((a > bb) == up) { keys[i] = bb; keys[p] = a; }
        }
      }
      __syncthreads();
    }
  }
  for (int i = tid; i < KSEL; i += 1024) sel[b * KSEL + i] = (int)(keys[i] & 0xffffffffu);
}

// ---------------- gate: mean over s, then softmax(mean @ w_gate + b) --------
__global__ __launch_bounds__(256) void gate1(const float* __restrict__ x,
                                             float* __restrict__ partial) {
  int b = blockIdx.y, chunk = blockIdx.x, tid = threadIdx.x;
  for (int c = tid; c < DD; c += 256) {
    const float* xp = x + ((long)(b * SS + chunk * 128)) * DD + c;
    float acc = 0.f;
    for (int s2 = 0; s2 < 128; ++s2) acc += xp[(long)s2 * DD];
    partial[(long)(b * 16 + chunk) * DD + c] = acc;
  }
}

__global__ __launch_bounds__(256) void gate2(const float* __restrict__ partial,
                                             const float* __restrict__ w_gate,
                                             const float* __restrict__ b_gate,
                                             float* __restrict__ fw) {
  int b = blockIdx.x, tid = threadIdx.x;
  __shared__ float meanbuf[DD];
  __shared__ float lg[3];
  for (int c = tid; c < DD; c += 256) {
    float acc = 0.f;
    for (int p = 0; p < 16; ++p) acc += partial[(long)(b * 16 + p) * DD + c];
    meanbuf[c] = acc * (1.0f / (float)SS);
  }
  __syncthreads();
  if (tid < 3) {
    float acc = b_gate[tid];
    for (int d = 0; d < DD; ++d) acc += meanbuf[d] * w_gate[d * 3 + tid];
    lg[tid] = acc;
  }
  __syncthreads();
  if (tid == 0) {
    float mx = fmaxf(lg[0], fmaxf(lg[1], lg[2]));
    float e0 = expf(lg[0] - mx), e1 = expf(lg[1] - mx), e2 = expf(lg[2] - mx);
    float inv = 1.f / (e0 + e1 + e2);
    fw[b * 3 + 0] = e0 * inv; fw[b * 3 + 1] = e1 * inv; fw[b * 3 + 2] = e2 * inv;
  }
}

// ---------------- MFMA GEMM: C = A(MxK) * BT(NxK)^T --------------------------
template <int OUT_BF16>
__global__ __launch_bounds__(256) void gemm_tile(const unsigned short* __restrict__ A,
                                                 const unsigned short* __restrict__ BT,
                                                 void* __restrict__ C,
                                                 const float* __restrict__ bias,
                                                 int N, int K) {
  __shared__ unsigned short As[128 * 32];
  __shared__ unsigned short Bs[128 * 32];
  const int tid = threadIdx.x;
  const int lane = tid & 63;
  const int wv = tid >> 6;
  const int wr = wv >> 1, wc = wv & 1;
  const long rowBase = (long)blockIdx.y * 128;
  const long colBase = (long)blockIdx.x * 128;

  f32x4 acc[4][4];
#pragma unroll
  for (int i = 0; i < 4; ++i)
#pragma unroll
    for (int j = 0; j < 4; ++j)
#pragma unroll
      for (int r = 0; r < 4; ++r) acc[i][j][r] = 0.f;

  const int g0 = tid, g1 = tid + 256;
  const int r0 = g0 >> 2, k80 = (g0 & 3) ^ ((r0 >> 1) & 3);
  const int r1 = g1 >> 2, k81 = (g1 & 3) ^ ((r1 >> 1) & 3);
  const unsigned short* ga0 = A + (rowBase + r0) * (long)K + k80 * 8;
  const unsigned short* ga1 = A + (rowBase + r1) * (long)K + k81 * 8;
  const unsigned short* gb0 = BT + (colBase + r0) * (long)K + k80 * 8;
  const unsigned short* gb1 = BT + (colBase + r1) * (long)K + k81 * 8;
  unsigned short* la0 = As + g0 * 8;
  unsigned short* la1 = As + g1 * 8;
  unsigned short* lb0 = Bs + g0 * 8;
  unsigned short* lb1 = Bs + g1 * 8;

  const int k8 = lane >> 4;
  const int fr = lane & 15;
  int aoff[4], boff[4];
#pragma unroll
  for (int i = 0; i < 4; ++i) {
    int rowA = wr * 64 + i * 16 + fr;
    aoff[i] = (rowA * 4 + (k8 ^ ((rowA >> 1) & 3))) * 8;
    int rowB = wc * 64 + i * 16 + fr;
    boff[i] = (rowB * 4 + (k8 ^ ((rowB >> 1) & 3))) * 8;
  }

  for (int kt = 0; kt < K; kt += 32) {
    gload_lds16(ga0 + kt, la0);
    gload_lds16(ga1 + kt, la1);
    gload_lds16(gb0 + kt, lb0);
    gload_lds16(gb1 + kt, lb1);
    __syncthreads();
    bf16x8 af[4], bfr[4];
#pragma unroll
    for (int i = 0; i < 4; ++i) af[i] = *(const bf16x8*)(As + aoff[i]);
#pragma unroll
    for (int i = 0; i < 4; ++i) bfr[i] = *(const bf16x8*)(Bs + boff[i]);
#pragma unroll
    for (int mi = 0; mi < 4; ++mi)
#pragma unroll
      for (int ni = 0; ni < 4; ++ni)
        acc[mi][ni] = __builtin_amdgcn_mfma_f32_16x16x32_bf16(af[mi], bfr[ni], acc[mi][ni], 0, 0, 0);
    __syncthreads();
  }

  const int orow0 = (lane >> 4) * 4;
#pragma unroll
  for (int mi = 0; mi < 4; ++mi) {
    long gr = rowBase + wr * 64 + mi * 16 + orow0;
#pragma unroll
    for (int ni = 0; ni < 4; ++ni) {
      long gc = colBase + wc * 64 + ni * 16 + fr;
#pragma unroll
      for (int r = 0; r < 4; ++r) {
        float v = acc[mi][ni][r];
        if (OUT_BF16) {
          ((unsigned short*)C)[(gr + r) * (long)N + gc] = f2b(v);
        } else {
          ((float*)C)[(gr + r) * (long)N + gc] = v + bias[gc];
        }
      }
    }
  }
}

// ---------------- gather top-k keys: Kg[b][j][c] (zero-padded to 448) -------
__global__ __launch_bounds__(256) void gather_k(const unsigned short* __restrict__ QKV,
                                                const int* __restrict__ sel,
                                                unsigned short* __restrict__ Kg) {
  int j = blockIdx.x;           // 0..447
  int b = blockIdx.y;
  int tid = threadIdx.x;
  if (tid >= 192) return;       // 192 * 8B = 1536B = 768 bf16
  uint2* dst = (uint2*)(Kg + ((long)b * KPAD + j) * DD);
  if (j < KSEL) {
    const uint2* src = (const uint2*)(QKV + ((long)b * SS + sel[b * KSEL + j]) * 4608 + 768);
    dst[tid] = src[tid];
  } else {
    dst[tid] = uint2{0u, 0u};
  }
}

// ---------------- gather top-k values transposed: Vt[b][c][j] ---------------
__global__ __launch_bounds__(256) void gather_vt(const unsigned short* __restrict__ QKV,
                                                 const int* __restrict__ sel,
                                                 unsigned short* __restrict__ Vt) {
  __shared__ unsigned short tile[16][68];
  int jt = blockIdx.x, ct = blockIdx.y, b = blockIdx.z;   // 28, 12, 2
  int tid = threadIdx.x;
  int jj = tid & 15, cl = tid >> 4;                        // cl 0..15, 4 c each
  int j = jt * 16 + jj;
  if (j < KSEL) {
    const unsigned short* src = QKV + ((long)b * SS + sel[b * KSEL + j]) * 4608 + 1536 + ct * 64;
    *(uint2*)&tile[jj][cl * 4] = *(const uint2*)&src[cl * 4];
  } else {
    *(uint2*)&tile[jj][cl * 4] = uint2{0u, 0u};
  }
  __syncthreads();
  int c = tid >> 2;             // 0..63
  int jl = (tid & 3) * 4;       // 0,4,8,12
  unsigned v0 = tile[jl + 0][c], v1 = tile[jl + 1][c];
  unsigned v2 = tile[jl + 2][c], v3 = tile[jl + 3][c];
  unsigned short* dst = Vt + ((long)b * DD + ct * 64 + c) * KPAD + jt * 16 + jl;
  *(uint2*)dst = uint2{v0 | (v1 << 16), v2 | (v3 << 16)};
}

// ---------------- full V transpose for local branch: Vtl[b][c][s] -----------
__global__ __launch_bounds__(256) void transpose_vl(const unsigned short* __restrict__ QKV,
                                                    unsigned short* __restrict__ Vtl) {
  __shared__ unsigned short tile[16][68];
  int jt = blockIdx.x, ct = blockIdx.y, b = blockIdx.z;   // 128, 12, 2
  int tid = threadIdx.x;
  int jj = tid & 15, cl = tid >> 4;
  const unsigned short* src = QKV + ((long)b * SS + jt * 16 + jj) * 4608 + 3840 + ct * 64;
  *(uint2*)&tile[jj][cl * 4] = *(const uint2*)&src[cl * 4];
  __syncthreads();
  int c = tid >> 2;
  int jl = (tid & 3) * 4;
  unsigned v0 = tile[jl + 0][c], v1 = tile[jl + 1][c];
  unsigned v2 = tile[jl + 2][c], v3 = tile[jl + 3][c];
  unsigned short* dst = Vtl + ((long)b * DD + ct * 64 + c) * (long)SS + jt * 16 + jl;
  *(uint2*)dst = uint2{v0 | (v1 << 16), v2 | (v3 << 16)};
}

// ---------------- temporal gathers: K8[b][16][768], Vt8[b][768][32] ---------
__global__ __launch_bounds__(256) void gather_t8(const unsigned short* __restrict__ QKVt,
                                                 unsigned short* __restrict__ K8,
                                                 unsigned short* __restrict__ Vt8) {
  int b = blockIdx.y;
  int c = blockIdx.x * 256 + threadIdx.x;   // grid.x = 3 -> c in [0,768)
#pragma unroll
  for (int j = 0; j < 8; ++j) {
    const unsigned short* src = QKVt + ((long)b * SS + j * 256) * 2304 + c;
    K8[((long)b * 16 + j) * DD + c]  = src[768];
    Vt8[((long)b * DD + c) * 32 + j] = src[1536];
  }
#pragma unroll
  for (int j = 8; j < 16; ++j) K8[((long)b * 16 + j) * DD + c] = 0;
#pragma unroll
  for (int j = 8; j < 32; ++j) Vt8[((long)b * DD + c) * 32 + j] = 0;
}

// ---------------- global-branch flash MFMA attention ------------------------
// 4 waves x 16 q (64 q/block), 7 kv-tiles of 64 keys, K/V double-buffered in
// LDS (global_load_lds, XOR-swizzled src + read), online softmax with running
// (m,l) per q-row, per-wave P tile in LDS. 2-phase pipeline: stage(t+1) issued
// before compute(t), single vmcnt(0)+barrier per tile.
__global__ __launch_bounds__(256) void attn_global_flash(
    const unsigned short* __restrict__ QKV,   // QKVx: q at col 0, ld 4608
    const unsigned short* __restrict__ Kg,    // [b][448][768]
    const unsigned short* __restrict__ Vt,    // [b][768][448]
    float* __restrict__ Outp) {               // [b*2048+q][768]
  __shared__ unsigned short Kl[2][64 * 64];
  __shared__ unsigned short Vl[2][64 * 64];
  __shared__ unsigned short Pl[4][16 * 68];
  int tid = threadIdx.x, w = tid >> 6, lane = tid & 63;
  int fr = lane & 15, g = lane >> 4;
  int b = blockIdx.y / HH, h = blockIdx.y % HH, hoff = h * 64;
  int qbase = blockIdx.x * 64 + w * 16;
  long qrow = (long)b * SS + qbase + fr;

  const unsigned short* qptr = QKV + qrow * 4608 + hoff + g * 8;
  bf16x8 bq0 = *(const bf16x8*)(qptr);
  bf16x8 bq1 = *(const bf16x8*)(qptr + 32);

  // staging geometry: LDS slot s (16B) <- row=s>>3, stored chunk cs=s&7,
  // actual global col-chunk c = cs ^ (row&7)  (inverse-swz source, rule #21)
  const int s0 = tid, s1 = tid + 256;
  const int r0 = s0 >> 3, c0 = (s0 & 7) ^ (r0 & 7);
  const int r1 = s1 >> 3, c1 = (s1 & 7) ^ (r1 & 7);
  const unsigned short* kg_b = Kg + (long)b * KPAD * DD + hoff;
  const unsigned short* vt_b = Vt + ((long)b * DD + hoff) * KPAD;

  auto stage = [&](int buf, int t0) {
    gload_lds16(kg_b + (long)(t0 * 64 + r0) * DD + c0 * 8, &Kl[buf][s0 * 8]);
    gload_lds16(kg_b + (long)(t0 * 64 + r1) * DD + c1 * 8, &Kl[buf][s1 * 8]);
    gload_lds16(vt_b + (long)r0 * KPAD + t0 * 64 + c0 * 8, &Vl[buf][s0 * 8]);
    gload_lds16(vt_b + (long)r1 * KPAD + t0 * 64 + c1 * 8, &Vl[buf][s1 * 8]);
  };

  f32x4 oacc[4];
#pragma unroll
  for (int mf = 0; mf < 4; ++mf)
#pragma unroll
    for (int r = 0; r < 4; ++r) oacc[mf][r] = 0.f;
  float m = -3.0e38f, l = 0.f;

  stage(0, 0);
  asm volatile("s_waitcnt vmcnt(0)" ::: "memory");
  __syncthreads();

  for (int t = 0; t < NKT; ++t) {
    int cur = t & 1;
    if (t + 1 < NKT) stage(cur ^ 1, t + 1);

    // QK^T: S^T tile (64 keys x 16 q), K from swizzled LDS
    f32x4 st[4];
#pragma unroll
    for (int kt = 0; kt < 4; ++kt) {
      int row = kt * 16 + fr;
      bf16x8 a0 = *(const bf16x8*)(&Kl[cur][(row * 8 + (g ^ (row & 7))) * 8]);
      bf16x8 a1 = *(const bf16x8*)(&Kl[cur][(row * 8 + ((4 + g) ^ (row & 7))) * 8]);
      f32x4 z = {0.f, 0.f, 0.f, 0.f};
      z = __builtin_amdgcn_mfma_f32_16x16x32_bf16(a0, bq0, z, 0, 0, 0);
      st[kt] = __builtin_amdgcn_mfma_f32_16x16x32_bf16(a1, bq1, z, 0, 0, 0);
    }

    // mask + scale + tile max (lane holds keys t*64 + kt*16 + g*4 + r, q=fr)
    float tm = -3.0e38f;
#pragma unroll
    for (int kt = 0; kt < 4; ++kt)
#pragma unroll
      for (int r = 0; r < 4; ++r) {
        int key = t * 64 + kt * 16 + g * 4 + r;
        float s = (key < KSEL) ? st[kt][r] * 0.125f : -1.0e30f;
        st[kt][r] = s;
        tm = fmaxf(tm, s);
      }
    tm = fmaxf(tm, __shfl_xor(tm, 16, 64));
    tm = fmaxf(tm, __shfl_xor(tm, 32, 64));
    float newm = fmaxf(m, tm);
    float f = __expf(m - newm);
    float tsum = 0.f;
#pragma unroll
    for (int kt = 0; kt < 4; ++kt)
#pragma unroll
      for (int r = 0; r < 4; ++r) {
        float e = __expf(st[kt][r] - newm);
        st[kt][r] = e;
        tsum += e;
      }
    tsum += __shfl_xor(tsum, 16, 64);
    tsum += __shfl_xor(tsum, 32, 64);
    l = l * f + tsum;
    m = newm;
#pragma unroll
    for (int mf = 0; mf < 4; ++mf)
#pragma unroll
      for (int r = 0; r < 4; ++r) oacc[mf][r] *= f;

    // P^T (bf16) to per-wave LDS: row q=fr (stride 68), col key
    unsigned short* pw = &Pl[w][fr * 68 + g * 4];
#pragma unroll
    for (int kt = 0; kt < 4; ++kt) {
      uint2 pk;
      pk.x = (unsigned)f2b(st[kt][0]) | ((unsigned)f2b(st[kt][1]) << 16);
      pk.y = (unsigned)f2b(st[kt][2]) | ((unsigned)f2b(st[kt][3]) << 16);
      *(uint2*)(pw + kt * 16) = pk;
    }

    // PV: O^T += Vt_tile (A) x P^T (B), V from swizzled LDS
    const unsigned short* prd = &Pl[w][fr * 68];
#pragma unroll
    for (int ks2 = 0; ks2 < 2; ++ks2) {
      bf16x8 pf = *(const bf16x8*)(prd + ks2 * 32 + g * 8);
#pragma unroll
      for (int mf = 0; mf < 4; ++mf) {
        int vr = mf * 16 + fr;
        int vc = ks2 * 4 + g;
        bf16x8 vf = *(const bf16x8*)(&Vl[cur][(vr * 8 + (vc ^ (vr & 7))) * 8]);
        oacc[mf] = __builtin_amdgcn_mfma_f32_16x16x32_bf16(vf, pf, oacc[mf], 0, 0, 0);
      }
    }

    asm volatile("s_waitcnt vmcnt(0)" ::: "memory");
    __syncthreads();
  }

  float inv = 1.f / l;
  float* orow = Outp + qrow * DD + hoff;
#pragma unroll
  for (int mf = 0; mf < 4; ++mf) {
    f32x4 ov;
#pragma unroll
    for (int r = 0; r < 4; ++r) ov[r] = oacc[mf][r] * inv;
    *(f32x4*)(orow + mf * 16 + g * 4) = ov;
  }
}

// ---------------- window MFMA attention (local / temporal) ------------------
template <int MODE>
__global__ __launch_bounds__(256) void attn_win_mfma(
    const unsigned short* __restrict__ QKV,   // MODE0: QKVx ld4608; MODE1: QKVt ld2304
    const unsigned short* __restrict__ K8,    // MODE1 only: [b][16][768]
    const unsigned short* __restrict__ Vt,    // MODE0: [b][768][2048]; MODE1: [b][768][32]
    float* __restrict__ Outp) {
  constexpr int LD   = (MODE == 0) ? 4608 : 2304;
  constexpr int QO   = (MODE == 0) ? 2304 : 0;
  constexpr int KO   = 3072;
  constexpr long VSTR = (MODE == 0) ? SS : 32;
  __shared__ unsigned short P_lds[4][16 * 40];
  int tid = threadIdx.x, w = tid >> 6, lane = tid & 63;
  int fr = lane & 15, g = lane >> 4;
  int b = blockIdx.y / HH, h = blockIdx.y % HH, hoff = h * 64;
  int qbase = blockIdx.x * 64 + w * 16;
  long qrow = (long)b * SS + qbase + fr;

  const unsigned short* qptr = QKV + qrow * LD + QO + hoff + g * 8;
  bf16x8 bq0 = *(const bf16x8*)(qptr);
  bf16x8 bq1 = *(const bf16x8*)(qptr + 32);

  int kstart = qbase - 8;
  if (kstart < 0) kstart = 0;
  if (kstart > SS - 32) kstart = SS - 32;

  f32x4 st[2];
  if (MODE == 0) {
#pragma unroll
    for (int kt = 0; kt < 2; ++kt) {
      const unsigned short* kp =
          QKV + ((long)b * SS + kstart + kt * 16 + fr) * LD + KO + hoff + g * 8;
      bf16x8 a0 = *(const bf16x8*)(kp);
      bf16x8 a1 = *(const bf16x8*)(kp + 32);
      f32x4 z = {0.f, 0.f, 0.f, 0.f};
      z = __builtin_amdgcn_mfma_f32_16x16x32_bf16(a0, bq0, z, 0, 0, 0);
      st[kt] = __builtin_amdgcn_mfma_f32_16x16x32_bf16(a1, bq1, z, 0, 0, 0);
    }
  } else {
    const unsigned short* kp = K8 + ((long)b * 16 + fr) * DD + hoff + g * 8;
    bf16x8 a0 = *(const bf16x8*)(kp);
    bf16x8 a1 = *(const bf16x8*)(kp + 32);
    f32x4 z = {0.f, 0.f, 0.f, 0.f};
    z = __builtin_amdgcn_mfma_f32_16x16x32_bf16(a0, bq0, z, 0, 0, 0);
    st[0] = __builtin_amdgcn_mfma_f32_16x16x32_bf16(a1, bq1, z, 0, 0, 0);
    st[1] = f32x4{0.f, 0.f, 0.f, 0.f};
  }

  float m = -3.0e38f;
#pragma unroll
  for (int kt = 0; kt < 2; ++kt)
#pragma unroll
    for (int r = 0; r < 4; ++r) {
      int idx = kt * 16 + g * 4 + r;
      bool valid;
      if (MODE == 0) {
        int rel = kstart + idx - qbase - fr;
        valid = (rel >= -8) && (rel <= 8);
      } else {
        valid = (idx < 8);
      }
      float s = valid ? st[kt][r] * 0.125f : -1.0e30f;
      st[kt][r] = s;
      m = fmaxf(m, s);
    }
  m = fmaxf(m, __shfl_xor(m, 16, 64));
  m = fmaxf(m, __shfl_xor(m, 32, 64));

  float lsum = 0.f;
#pragma unroll
  for (int kt = 0; kt < 2; ++kt)
#pragma unroll
    for (int r = 0; r < 4; ++r) {
      float e = __expf(st[kt][r] - m);
      st[kt][r] = e;
      lsum += e;
    }
  lsum += __shfl_xor(lsum, 16, 64);
  lsum += __shfl_xor(lsum, 32, 64);

  unsigned short* pl = &P_lds[w][fr * 40 + g * 4];
#pragma unroll
  for (int kt = 0; kt < 2; ++kt) {
    uint2 pk;
    pk.x = (unsigned)f2b(st[kt][0]) | ((unsigned)f2b(st[kt][1]) << 16);
    pk.y = (unsigned)f2b(st[kt][2]) | ((unsigned)f2b(st[kt][3]) << 16);
    *(uint2*)(pl + kt * 16) = pk;
  }

  f32x4 oacc[4];
#pragma unroll
  for (int mf = 0; mf < 4; ++mf)
#pragma unroll
    for (int r = 0; r < 4; ++r) oacc[mf][r] = 0.f;

  const unsigned short* pr = &P_lds[w][fr * 40 + g * 8];
  bf16x8 pf = *(const bf16x8*)(pr);
  long kb2 = (MODE == 0) ? kstart : 0;
#pragma unroll
  for (int mf = 0; mf < 4; ++mf) {
    const unsigned short* vp =
        Vt + ((long)b * DD + hoff + mf * 16 + fr) * VSTR + kb2 + g * 8;
    bf16x8 vf = *(const bf16x8*)(vp);
    oacc[mf] = __builtin_amdgcn_mfma_f32_16x16x32_bf16(vf, pf, oacc[mf], 0, 0, 0);
  }

  float inv = 1.f / lsum;
  float* orow = Outp + qrow * DD + hoff;
#pragma unroll
  for (int mf = 0; mf < 4; ++mf) {
    f32x4 ov;
#pragma unroll
    for (int r = 0; r < 4; ++r) ov[r] = oacc[mf][r] * inv;
    *(f32x4*)(orow + mf * 16 + g * 4) = ov;
  }
}

// ---------------- layernorm + gate scale + concat to bf16 -------------------
__global__ __launch_bounds__(256) void ln_gate_concat(
    const float* __restrict__ gsrc, const float* __restrict__ lsrc, const float* __restrict__ tsrc,
    const float* __restrict__ gg, const float* __restrict__ gb,
    const float* __restrict__ lgam, const float* __restrict__ lbet,
    const float* __restrict__ tg, const float* __restrict__ tb,
    const float* __restrict__ fw, unsigned short* __restrict__ comb) {
  int row = blockIdx.x;
  int b = row >> 11;
  int tid = threadIdx.x;
  __shared__ float red[8];
  const float* srcs[3] = {gsrc, lsrc, tsrc};
  const float* gams[3] = {gg, lgam, tg};
  const float* bets[3] = {gb, lbet, tb};
#pragma unroll
  for (int br = 0; br < 3; ++br) {
    const float* src = srcs[br] + (long)row * DD;
    float x0 = src[tid], x1 = src[tid + 256], x2 = src[tid + 512];
    float s = x0 + x1 + x2;
    float ss = x0 * x0 + x1 * x1 + x2 * x2;
#pragma unroll
    for (int msk = 1; msk < 64; msk <<= 1) {
      s += __shfl_xor(s, msk, 64);
      ss += __shfl_xor(ss, msk, 64);
    }
    int wv = tid >> 6, lane = tid & 63;
    if (lane == 0) { red[wv] = s; red[4 + wv] = ss; }
    __syncthreads();
    float S4 = red[0] + red[1] + red[2] + red[3];
    float SQ = red[4] + red[5] + red[6] + red[7];
    float mean = S4 * (1.f / (float)DD);
    float var = SQ * (1.f / (float)DD) - mean * mean;
    float rs = rsqrtf(var + 1e-5f);
    float gate = fw[b * 3 + br];
    const float* gam = gams[br];
    const float* bet = bets[br];
    unsigned short* dst = comb + (long)row * 2304 + br * DD;
    dst[tid]       = f2b(((x0 - mean) * rs * gam[tid]       + bet[tid])       * gate);
    dst[tid + 256] = f2b(((x1 - mean) * rs * gam[tid + 256] + bet[tid + 256]) * gate);
    dst[tid + 512] = f2b(((x2 - mean) * rs * gam[tid + 512] + bet[tid + 512]) * gate);
    __syncthreads();
  }
}

// ---------------- launcher ---------------------------------------------------
extern "C" void kernel_launch(void* const* d_in, const int* in_sizes, int n_in,
                              void* d_out, int out_size, void* d_ws, size_t ws_size,
                              hipStream_t stream) {
  const float* x        = (const float*)d_in[0];
  const float* wgq      = (const float*)d_in[1];
  const float* wgk      = (const float*)d_in[2];
  const float* wgv      = (const float*)d_in[3];
  const float* wlq      = (const float*)d_in[4];
  const float* wlk      = (const float*)d_in[5];
  const float* wlv      = (const float*)d_in[6];
  const float* wtq      = (const float*)d_in[7];
  const float* wtk      = (const float*)d_in[8];
  const float* wtv      = (const float*)d_in[9];
  const float* w_out    = (const float*)d_in[10];
  const float* b_out    = (const float*)d_in[11];
  const float* w_gate   = (const float*)d_in[12];
  const float* b_gate   = (const float*)d_in[13];
  const float* w_sparse = (const float*)d_in[14];
  const float* b_sparse = (const float*)d_in[15];
  const float* g_gamma  = (const float*)d_in[16];
  const float* g_beta   = (const float*)d_in[17];
  const float* l_gamma  = (const float*)d_in[18];
  const float* l_beta   = (const float*)d_in[19];
  const float* t_gamma  = (const float*)d_in[20];
  const float* t_beta   = (const float*)d_in[21];
  float* outp = (float*)d_out;

  unsigned short* xb   = (unsigned short*)d_ws;
  unsigned short* xpb  = xb  + (long)NTOK * DD;
  unsigned short* WTx  = xpb + (long)NTOK * DD;
  unsigned short* WTt  = WTx + (long)4608 * DD;
  unsigned short* WTo  = WTt + (long)2304 * DD;
  unsigned short* QKVx = WTo + (long)DD * 2304;
  unsigned short* QKVt = QKVx + (long)NTOK * 4608;
  unsigned short* comb = QKVt + (long)NTOK * 2304;
  float* gout    = (float*)(comb + (long)NTOK * 2304);
  float* lout    = gout + (long)NTOK * DD;
  float* tout    = lout + (long)NTOK * DD;
  float* imp     = tout + (long)NTOK * DD;
  float* partial = imp + NTOK;
  float* fw      = partial + 32 * DD;
  int*   sel     = (int*)(fw + 8);
  unsigned short* Kg = (unsigned short*)(sel + 832);     // [2][448][768]
  unsigned short* Vt = Kg + (long)BB * KPAD * DD;        // [2][768][448]
  // buffer reuse (stream-ordered; xb/xpb dead after the projection GEMMs):
  unsigned short* Vtl = xpb;                             // [2][768][2048]
  unsigned short* K8  = xb;                              // [2][16][768]
  unsigned short* Vt8 = xb + (long)BB * 16 * DD;         // [2][768][32]

  prep_x<<<NTOK * DD / 256, 256, 0, stream>>>(x, xb, xpb);
  transpose_all<<<dim3(24, 72, 10), dim3(32, 8), 0, stream>>>(
      wgq, wgk, wgv, wlq, wlk, wlv, wtq, wtk, wtv, w_out, WTx, WTt, WTo);
  imp_kernel<<<NTOK / 4, 256, 0, stream>>>(x, w_sparse, b_sparse, imp);
  topk_kernel<<<BB, 1024, 0, stream>>>(imp, sel);
  gate1<<<dim3(16, BB), 256, 0, stream>>>(x, partial);
  gate2<<<BB, 256, 0, stream>>>(partial, w_gate, b_gate, fw);

  gemm_tile<1><<<dim3(36, 32), 256, 0, stream>>>(xb,  WTx, QKVx, nullptr, 4608, DD);
  gemm_tile<1><<<dim3(18, 32), 256, 0, stream>>>(xpb, WTt, QKVt, nullptr, 2304, DD);

  gather_k<<<dim3(KPAD, BB), 256, 0, stream>>>(QKVx, sel, Kg);
  gather_vt<<<dim3(28, 12, BB), 256, 0, stream>>>(QKVx, sel, Vt);
  attn_global_flash<<<dim3(32, BB * HH), 256, 0, stream>>>(QKVx, Kg, Vt, gout);

  transpose_vl<<<dim3(128, 12, BB), 256, 0, stream>>>(QKVx, Vtl);
  gather_t8<<<dim3(3, BB), 256, 0, stream>>>(QKVt, K8, Vt8);
  attn_win_mfma<0><<<dim3(32, BB * HH), 256, 0, stream>>>(QKVx, nullptr, Vtl, lout);
  attn_win_mfma<1><<<dim3(32, BB * HH), 256, 0, stream>>>(QKVt, K8, Vt8, tout);

  ln_gate_concat<<<NTOK, 256, 0, stream>>>(gout, lout, tout, g_gamma, g_beta,
                                           l_gamma, l_beta, t_gamma, t_beta, fw, comb);
  gemm_tile<0><<<dim3(6, 32), 256, 0, stream>>>(comb, WTo, outp, b_out, 768, 2304);
}

// Round 7
// 267.390 us; speedup vs baseline: 7.2746x; 1.0490x over previous
//
#include <hip/hip_runtime.h>
#include <cstdint>

// Problem constants
constexpr int BB   = 2;
constexpr int SS   = 2048;
constexpr int DD   = 768;
constexpr int HH   = 12;
constexpr int NTOK = BB * SS;          // 4096
constexpr int KSEL = 409;              // int((1-0.8)*2048)
constexpr int KPAD = 448;              // 7 kv-tiles of 64
constexpr int NKT  = 7;                // kv tiles of 64 keys

typedef __bf16 bf16x8 __attribute__((ext_vector_type(8)));
typedef float  f32x4  __attribute__((ext_vector_type(4)));

__device__ __forceinline__ float b2f(unsigned short u) {
  return __uint_as_float(((unsigned)u) << 16);
}
__device__ __forceinline__ unsigned short f2b(float f) {
  unsigned u = __float_as_uint(f);
  u += 0x7fffu + ((u >> 16) & 1u);   // RNE
  return (unsigned short)(u >> 16);
}

__device__ __forceinline__ void gload_lds16(const void* gsrc, void* ldst) {
  __builtin_amdgcn_global_load_lds(
      (__attribute__((address_space(1))) void*)(gsrc),
      (__attribute__((address_space(3))) void*)(ldst), 16, 0, 0);
}

// -------- fused prep: xb, xpb (=x+PE), importance = x @ w_sparse + b --------
__global__ __launch_bounds__(256) void prep_imp(const float* __restrict__ x,
                                                const float* __restrict__ wsp,
                                                const float* __restrict__ bsp,
                                                unsigned short* __restrict__ xb,
                                                unsigned short* __restrict__ xpb,
                                                float* __restrict__ imp) {
  int row = blockIdx.x;                 // 0..4095
  int srow = row & (SS - 1);
  int tid = threadIdx.x;
  const float* xr = x + (long)row * DD;
  float acc = 0.f;
#pragma unroll
  for (int k = 0; k < 3; ++k) {
    int c = tid + k * 256;
    float xv = xr[c];
    xb[(long)row * DD + c] = f2b(xv);
    int j2 = c & ~1;
    float freq = __expf((float)j2 * -0.011992630692677323f);  // exp(-j2*ln(1e4)/768)
    float ang = (float)srow * freq;
    float pe = (c & 1) ? cosf(ang) : sinf(ang);
    xpb[(long)row * DD + c] = f2b(xv + pe);
    acc += xv * wsp[c];
  }
#pragma unroll
  for (int m = 1; m < 64; m <<= 1) acc += __shfl_xor(acc, m, 64);
  __shared__ float red[4];
  int wv = tid >> 6, lane = tid & 63;
  if (lane == 0) red[wv] = acc;
  __syncthreads();
  if (tid == 0) imp[row] = red[0] + red[1] + red[2] + red[3] + bsp[0];
}

// ---------------- transpose all weights to bf16 B^T (N x K) -----------------
__global__ void transpose_all(const float* w0, const float* w1, const float* w2,
                              const float* w3, const float* w4, const float* w5,
                              const float* w6, const float* w7, const float* w8,
                              const float* w9,
                              unsigned short* WTx, unsigned short* WTt,
                              unsigned short* WTo) {
  __shared__ float tile[32][33];
  int z = blockIdx.z;
  const float* src;
  unsigned short* dst;
  int R;
  if (z < 6)      { const float* a[6] = {w0,w1,w2,w3,w4,w5}; src = a[z];   dst = WTx + (long)z*DD*DD;     R = DD;   }
  else if (z < 9) { const float* a[3] = {w6,w7,w8};          src = a[z-6]; dst = WTt + (long)(z-6)*DD*DD; R = DD;   }
  else            { src = w9; dst = WTo; R = 2304; }
  int r0 = blockIdx.y * 32;
  if (r0 >= R) return;
  int c0 = blockIdx.x * 32;
  int tx = threadIdx.x, ty = threadIdx.y;
  for (int i = ty; i < 32; i += 8) tile[i][tx] = src[(long)(r0 + i) * DD + c0 + tx];
  __syncthreads();
  for (int i = ty; i < 32; i += 8) dst[(long)(c0 + i) * R + r0 + tx] = f2b(tile[tx][i]);
}

// ---------------- top-k via bitonic sort (value desc, index asc) ------------
__global__ __launch_bounds__(1024) void topk_kernel(const float* __restrict__ imp,
                                                    int* __restrict__ sel) {
  __shared__ unsigned long long keys[SS];
  int b = blockIdx.x, tid = threadIdx.x;
  for (int i = tid; i < SS; i += 1024) {
    float v = imp[b * SS + i];
    unsigned u = __float_as_uint(v);
    u = (u & 0x80000000u) ? ~u : (u | 0x80000000u);   // ascending-order map
    unsigned du = ~u;                                  // descending
    keys[i] = ((unsigned long long)du << 32) | (unsigned)i;
  }
  __syncthreads();
  for (int k = 2; k <= SS; k <<= 1) {
    for (int j = k >> 1; j > 0; j >>= 1) {
      for (int i = tid; i < SS; i += 1024) {
        int p = i ^ j;
        if (p > i) {
          unsigned long long a = keys[i], bb = keys[p];
          bool up = ((i & k) == 0);
          if ((a > bb) == up) { keys[i] = bb; keys[p] = a; }
        }
      }
      __syncthreads();
    }
  }
  for (int i = tid; i < KSEL; i += 1024) sel[b * KSEL + i] = (int)(keys[i] & 0xffffffffu);
}

// ---------------- gate: mean over s, then softmax(mean @ w_gate + b) --------
__global__ __launch_bounds__(256) void gate1(const float* __restrict__ x,
                                             float* __restrict__ partial) {
  int b = blockIdx.y, chunk = blockIdx.x, tid = threadIdx.x;
  for (int c = tid; c < DD; c += 256) {
    const float* xp = x + ((long)(b * SS + chunk * 128)) * DD + c;
    float acc = 0.f;
    for (int s2 = 0; s2 < 128; ++s2) acc += xp[(long)s2 * DD];
    partial[(long)(b * 16 + chunk) * DD + c] = acc;
  }
}

__global__ __launch_bounds__(256) void gate2(const float* __restrict__ partial,
                                             const float* __restrict__ w_gate,
                                             const float* __restrict__ b_gate,
                                             float* __restrict__ fw) {
  int b = blockIdx.x, tid = threadIdx.x;
  __shared__ float meanbuf[DD];
  __shared__ float lg[3];
  for (int c = tid; c < DD; c += 256) {
    float acc = 0.f;
    for (int p = 0; p < 16; ++p) acc += partial[(long)(b * 16 + p) * DD + c];
    meanbuf[c] = acc * (1.0f / (float)SS);
  }
  __syncthreads();
  if (tid < 3) {
    float acc = b_gate[tid];
    for (int d = 0; d < DD; ++d) acc += meanbuf[d] * w_gate[d * 3 + tid];
    lg[tid] = acc;
  }
  __syncthreads();
  if (tid == 0) {
    float mx = fmaxf(lg[0], fmaxf(lg[1], lg[2]));
    float e0 = expf(lg[0] - mx), e1 = expf(lg[1] - mx), e2 = expf(lg[2] - mx);
    float inv = 1.f / (e0 + e1 + e2);
    fw[b * 3 + 0] = e0 * inv; fw[b * 3 + 1] = e1 * inv; fw[b * 3 + 2] = e2 * inv;
  }
}

// ---------------- MFMA GEMM: C = A(MxK) * BT(NxK)^T --------------------------
// 128x128 tile, BK=32, 2-phase double-buffered staging (stage t+1 before
// compute t), XCD-aware bijective block swizzle (requires nwg % 8 == 0).
template <int OUT_BF16>
__global__ __launch_bounds__(256) void gemm_tile(const unsigned short* __restrict__ A,
                                                 const unsigned short* __restrict__ BT,
                                                 void* __restrict__ C,
                                                 const float* __restrict__ bias,
                                                 int N, int K) {
  __shared__ unsigned short As[2][128 * 32];
  __shared__ unsigned short Bs[2][128 * 32];
  const int tid = threadIdx.x;
  const int lane = tid & 63;
  const int wv = tid >> 6;
  const int wr = wv >> 1, wc = wv & 1;

  // XCD swizzle: consecutive orig ids round-robin XCDs; give each XCD a
  // contiguous chunk instead (bijective since nwg % 8 == 0).
  int lin = blockIdx.y * gridDim.x + blockIdx.x;
  int chunk = (gridDim.x * gridDim.y) >> 3;
  int swz = (lin & 7) * chunk + (lin >> 3);
  const long rowBase = (long)(swz / gridDim.x) * 128;
  const long colBase = (long)(swz % gridDim.x) * 128;

  f32x4 acc[4][4];
#pragma unroll
  for (int i = 0; i < 4; ++i)
#pragma unroll
    for (int j = 0; j < 4; ++j)
#pragma unroll
      for (int r = 0; r < 4; ++r) acc[i][j][r] = 0.f;

  const int g0 = tid, g1 = tid + 256;
  const int r0 = g0 >> 2, k80 = (g0 & 3) ^ ((r0 >> 1) & 3);
  const int r1 = g1 >> 2, k81 = (g1 & 3) ^ ((r1 >> 1) & 3);
  const unsigned short* ga0 = A + (rowBase + r0) * (long)K + k80 * 8;
  const unsigned short* ga1 = A + (rowBase + r1) * (long)K + k81 * 8;
  const unsigned short* gb0 = BT + (colBase + r0) * (long)K + k80 * 8;
  const unsigned short* gb1 = BT + (colBase + r1) * (long)K + k81 * 8;

  const int k8 = lane >> 4;
  const int fr = lane & 15;
  int aoff[4], boff[4];
#pragma unroll
  for (int i = 0; i < 4; ++i) {
    int rowA = wr * 64 + i * 16 + fr;
    aoff[i] = (rowA * 4 + (k8 ^ ((rowA >> 1) & 3))) * 8;
    int rowB = wc * 64 + i * 16 + fr;
    boff[i] = (rowB * 4 + (k8 ^ ((rowB >> 1) & 3))) * 8;
  }

  auto stage = [&](int buf, int t) {
    int ko = t * 32;
    gload_lds16(ga0 + ko, &As[buf][g0 * 8]);
    gload_lds16(ga1 + ko, &As[buf][g1 * 8]);
    gload_lds16(gb0 + ko, &Bs[buf][g0 * 8]);
    gload_lds16(gb1 + ko, &Bs[buf][g1 * 8]);
  };

  const int nk = K >> 5;
  stage(0, 0);
  __syncthreads();
  for (int t = 0; t < nk; ++t) {
    int cur = t & 1;
    if (t + 1 < nk) stage(cur ^ 1, t + 1);
    bf16x8 af[4], bfr[4];
#pragma unroll
    for (int i = 0; i < 4; ++i) af[i] = *(const bf16x8*)(&As[cur][aoff[i]]);
#pragma unroll
    for (int i = 0; i < 4; ++i) bfr[i] = *(const bf16x8*)(&Bs[cur][boff[i]]);
#pragma unroll
    for (int mi = 0; mi < 4; ++mi)
#pragma unroll
      for (int ni = 0; ni < 4; ++ni)
        acc[mi][ni] = __builtin_amdgcn_mfma_f32_16x16x32_bf16(af[mi], bfr[ni], acc[mi][ni], 0, 0, 0);
    __syncthreads();   // drains vmcnt for the t+1 stage + protects buffers
  }

  const int orow0 = (lane >> 4) * 4;
#pragma unroll
  for (int mi = 0; mi < 4; ++mi) {
    long gr = rowBase + wr * 64 + mi * 16 + orow0;
#pragma unroll
    for (int ni = 0; ni < 4; ++ni) {
      long gc = colBase + wc * 64 + ni * 16 + fr;
#pragma unroll
      for (int r = 0; r < 4; ++r) {
        float v = acc[mi][ni][r];
        if (OUT_BF16) {
          ((unsigned short*)C)[(gr + r) * (long)N + gc] = f2b(v);
        } else {
          ((float*)C)[(gr + r) * (long)N + gc] = v + bias[gc];
        }
      }
    }
  }
}

// ---------------- gather top-k keys: Kg[b][j][c] (zero-padded to 448) -------
__global__ __launch_bounds__(256) void gather_k(const unsigned short* __restrict__ QKV,
                                                const int* __restrict__ sel,
                                                unsigned short* __restrict__ Kg) {
  int j = blockIdx.x;           // 0..447
  int b = blockIdx.y;
  int tid = threadIdx.x;
  if (tid >= 192) return;       // 192 * 8B = 1536B = 768 bf16
  uint2* dst = (uint2*)(Kg + ((long)b * KPAD + j) * DD);
  if (j < KSEL) {
    const uint2* src = (const uint2*)(QKV + ((long)b * SS + sel[b * KSEL + j]) * 4608 + 768);
    dst[tid] = src[tid];
  } else {
    dst[tid] = uint2{0u, 0u};
  }
}

// ---------------- gather top-k values transposed: Vt[b][c][j] ---------------
__global__ __launch_bounds__(256) void gather_vt(const unsigned short* __restrict__ QKV,
                                                 const int* __restrict__ sel,
                                                 unsigned short* __restrict__ Vt) {
  __shared__ unsigned short tile[16][68];
  int jt = blockIdx.x, ct = blockIdx.y, b = blockIdx.z;   // 28, 12, 2
  int tid = threadIdx.x;
  int jj = tid & 15, cl = tid >> 4;                        // cl 0..15, 4 c each
  int j = jt * 16 + jj;
  if (j < KSEL) {
    const unsigned short* src = QKV + ((long)b * SS + sel[b * KSEL + j]) * 4608 + 1536 + ct * 64;
    *(uint2*)&tile[jj][cl * 4] = *(const uint2*)&src[cl * 4];
  } else {
    *(uint2*)&tile[jj][cl * 4] = uint2{0u, 0u};
  }
  __syncthreads();
  int c = tid >> 2;             // 0..63
  int jl = (tid & 3) * 4;       // 0,4,8,12
  unsigned v0 = tile[jl + 0][c], v1 = tile[jl + 1][c];
  unsigned v2 = tile[jl + 2][c], v3 = tile[jl + 3][c];
  unsigned short* dst = Vt + ((long)b * DD + ct * 64 + c) * KPAD + jt * 16 + jl;
  *(uint2*)dst = uint2{v0 | (v1 << 16), v2 | (v3 << 16)};
}

// ---------------- full V transpose for local branch: Vtl[b][c][s] -----------
__global__ __launch_bounds__(256) void transpose_vl(const unsigned short* __restrict__ QKV,
                                                    unsigned short* __restrict__ Vtl) {
  __shared__ unsigned short tile[16][68];
  int jt = blockIdx.x, ct = blockIdx.y, b = blockIdx.z;   // 128, 12, 2
  int tid = threadIdx.x;
  int jj = tid & 15, cl = tid >> 4;
  const unsigned short* src = QKV + ((long)b * SS + jt * 16 + jj) * 4608 + 3840 + ct * 64;
  *(uint2*)&tile[jj][cl * 4] = *(const uint2*)&src[cl * 4];
  __syncthreads();
  int c = tid >> 2;
  int jl = (tid & 3) * 4;
  unsigned v0 = tile[jl + 0][c], v1 = tile[jl + 1][c];
  unsigned v2 = tile[jl + 2][c], v3 = tile[jl + 3][c];
  unsigned short* dst = Vtl + ((long)b * DD + ct * 64 + c) * (long)SS + jt * 16 + jl;
  *(uint2*)dst = uint2{v0 | (v1 << 16), v2 | (v3 << 16)};
}

// ---------------- temporal gathers: K8[b][16][768], Vt8[b][768][32] ---------
__global__ __launch_bounds__(256) void gather_t8(const unsigned short* __restrict__ QKVt,
                                                 unsigned short* __restrict__ K8,
                                                 unsigned short* __restrict__ Vt8) {
  int b = blockIdx.y;
  int c = blockIdx.x * 256 + threadIdx.x;   // grid.x = 3 -> c in [0,768)
#pragma unroll
  for (int j = 0; j < 8; ++j) {
    const unsigned short* src = QKVt + ((long)b * SS + j * 256) * 2304 + c;
    K8[((long)b * 16 + j) * DD + c]  = src[768];
    Vt8[((long)b * DD + c) * 32 + j] = src[1536];
  }
#pragma unroll
  for (int j = 8; j < 16; ++j) K8[((long)b * 16 + j) * DD + c] = 0;
#pragma unroll
  for (int j = 8; j < 32; ++j) Vt8[((long)b * DD + c) * 32 + j] = 0;
}

// ---------------- global-branch flash MFMA attention ------------------------
__global__ __launch_bounds__(256) void attn_global_flash(
    const unsigned short* __restrict__ QKV,   // QKVx: q at col 0, ld 4608
    const unsigned short* __restrict__ Kg,    // [b][448][768]
    const unsigned short* __restrict__ Vt,    // [b][768][448]
    float* __restrict__ Outp) {               // [b*2048+q][768]
  __shared__ unsigned short Kl[2][64 * 64];
  __shared__ unsigned short Vl[2][64 * 64];
  __shared__ unsigned short Pl[4][16 * 68];
  int tid = threadIdx.x, w = tid >> 6, lane = tid & 63;
  int fr = lane & 15, g = lane >> 4;
  int b = blockIdx.y / HH, h = blockIdx.y % HH, hoff = h * 64;
  int qbase = blockIdx.x * 64 + w * 16;
  long qrow = (long)b * SS + qbase + fr;

  const unsigned short* qptr = QKV + qrow * 4608 + hoff + g * 8;
  bf16x8 bq0 = *(const bf16x8*)(qptr);
  bf16x8 bq1 = *(const bf16x8*)(qptr + 32);

  const int s0 = tid, s1 = tid + 256;
  const int r0 = s0 >> 3, c0 = (s0 & 7) ^ (r0 & 7);
  const int r1 = s1 >> 3, c1 = (s1 & 7) ^ (r1 & 7);
  const unsigned short* kg_b = Kg + (long)b * KPAD * DD + hoff;
  const unsigned short* vt_b = Vt + ((long)b * DD + hoff) * KPAD;

  auto stage = [&](int buf, int t0) {
    gload_lds16(kg_b + (long)(t0 * 64 + r0) * DD + c0 * 8, &Kl[buf][s0 * 8]);
    gload_lds16(kg_b + (long)(t0 * 64 + r1) * DD + c1 * 8, &Kl[buf][s1 * 8]);
    gload_lds16(vt_b + (long)r0 * KPAD + t0 * 64 + c0 * 8, &Vl[buf][s0 * 8]);
    gload_lds16(vt_b + (long)r1 * KPAD + t0 * 64 + c1 * 8, &Vl[buf][s1 * 8]);
  };

  f32x4 oacc[4];
#pragma unroll
  for (int mf = 0; mf < 4; ++mf)
#pragma unroll
    for (int r = 0; r < 4; ++r) oacc[mf][r] = 0.f;
  float m = -3.0e38f, l = 0.f;

  stage(0, 0);
  asm volatile("s_waitcnt vmcnt(0)" ::: "memory");
  __syncthreads();

  for (int t = 0; t < NKT; ++t) {
    int cur = t & 1;
    if (t + 1 < NKT) stage(cur ^ 1, t + 1);

    f32x4 st[4];
#pragma unroll
    for (int kt = 0; kt < 4; ++kt) {
      int row = kt * 16 + fr;
      bf16x8 a0 = *(const bf16x8*)(&Kl[cur][(row * 8 + (g ^ (row & 7))) * 8]);
      bf16x8 a1 = *(const bf16x8*)(&Kl[cur][(row * 8 + ((4 + g) ^ (row & 7))) * 8]);
      f32x4 z = {0.f, 0.f, 0.f, 0.f};
      z = __builtin_amdgcn_mfma_f32_16x16x32_bf16(a0, bq0, z, 0, 0, 0);
      st[kt] = __builtin_amdgcn_mfma_f32_16x16x32_bf16(a1, bq1, z, 0, 0, 0);
    }

    float tm = -3.0e38f;
#pragma unroll
    for (int kt = 0; kt < 4; ++kt)
#pragma unroll
      for (int r = 0; r < 4; ++r) {
        int key = t * 64 + kt * 16 + g * 4 + r;
        float s = (key < KSEL) ? st[kt][r] * 0.125f : -1.0e30f;
        st[kt][r] = s;
        tm = fmaxf(tm, s);
      }
    tm = fmaxf(tm, __shfl_xor(tm, 16, 64));
    tm = fmaxf(tm, __shfl_xor(tm, 32, 64));
    float newm = fmaxf(m, tm);
    float f = __expf(m - newm);
    float tsum = 0.f;
#pragma unroll
    for (int kt = 0; kt < 4; ++kt)
#pragma unroll
      for (int r = 0; r < 4; ++r) {
        float e = __expf(st[kt][r] - newm);
        st[kt][r] = e;
        tsum += e;
      }
    tsum += __shfl_xor(tsum, 16, 64);
    tsum += __shfl_xor(tsum, 32, 64);
    l = l * f + tsum;
    m = newm;
#pragma unroll
    for (int mf = 0; mf < 4; ++mf)
#pragma unroll
      for (int r = 0; r < 4; ++r) oacc[mf][r] *= f;

    unsigned short* pw = &Pl[w][fr * 68 + g * 4];
#pragma unroll
    for (int kt = 0; kt < 4; ++kt) {
      uint2 pk;
      pk.x = (unsigned)f2b(st[kt][0]) | ((unsigned)f2b(st[kt][1]) << 16);
      pk.y = (unsigned)f2b(st[kt][2]) | ((unsigned)f2b(st[kt][3]) << 16);
      *(uint2*)(pw + kt * 16) = pk;
    }

    const unsigned short* prd = &Pl[w][fr * 68];
#pragma unroll
    for (int ks2 = 0; ks2 < 2; ++ks2) {
      bf16x8 pf = *(const bf16x8*)(prd + ks2 * 32 + g * 8);
#pragma unroll
      for (int mf = 0; mf < 4; ++mf) {
        int vr = mf * 16 + fr;
        int vc = ks2 * 4 + g;
        bf16x8 vf = *(const bf16x8*)(&Vl[cur][(vr * 8 + (vc ^ (vr & 7))) * 8]);
        oacc[mf] = __builtin_amdgcn_mfma_f32_16x16x32_bf16(vf, pf, oacc[mf], 0, 0, 0);
      }
    }

    asm volatile("s_waitcnt vmcnt(0)" ::: "memory");
    __syncthreads();
  }

  float inv = 1.f / l;
  float* orow = Outp + qrow * DD + hoff;
#pragma unroll
  for (int mf = 0; mf < 4; ++mf) {
    f32x4 ov;
#pragma unroll
    for (int r = 0; r < 4; ++r) ov[r] = oacc[mf][r] * inv;
    *(f32x4*)(orow + mf * 16 + g * 4) = ov;
  }
}

// ---------------- window MFMA attention (local / temporal) ------------------
template <int MODE>
__global__ __launch_bounds__(256) void attn_win_mfma(
    const unsigned short* __restrict__ QKV,   // MODE0: QKVx ld4608; MODE1: QKVt ld2304
    const unsigned short* __restrict__ K8,    // MODE1 only: [b][16][768]
    const unsigned short* __restrict__ Vt,    // MODE0: [b][768][2048]; MODE1: [b][768][32]
    float* __restrict__ Outp) {
  constexpr int LD   = (MODE == 0) ? 4608 : 2304;
  constexpr int QO   = (MODE == 0) ? 2304 : 0;
  constexpr int KO   = 3072;
  constexpr long VSTR = (MODE == 0) ? SS : 32;
  __shared__ unsigned short P_lds[4][16 * 40];
  int tid = threadIdx.x, w = tid >> 6, lane = tid & 63;
  int fr = lane & 15, g = lane >> 4;
  int b = blockIdx.y / HH, h = blockIdx.y % HH, hoff = h * 64;
  int qbase = blockIdx.x * 64 + w * 16;
  long qrow = (long)b * SS + qbase + fr;

  const unsigned short* qptr = QKV + qrow * LD + QO + hoff + g * 8;
  bf16x8 bq0 = *(const bf16x8*)(qptr);
  bf16x8 bq1 = *(const bf16x8*)(qptr + 32);

  int kstart = qbase - 8;
  if (kstart < 0) kstart = 0;
  if (kstart > SS - 32) kstart = SS - 32;

  f32x4 st[2];
  if (MODE == 0) {
#pragma unroll
    for (int kt = 0; kt < 2; ++kt) {
      const unsigned short* kp =
          QKV + ((long)b * SS + kstart + kt * 16 + fr) * LD + KO + hoff + g * 8;
      bf16x8 a0 = *(const bf16x8*)(kp);
      bf16x8 a1 = *(const bf16x8*)(kp + 32);
      f32x4 z = {0.f, 0.f, 0.f, 0.f};
      z = __builtin_amdgcn_mfma_f32_16x16x32_bf16(a0, bq0, z, 0, 0, 0);
      st[kt] = __builtin_amdgcn_mfma_f32_16x16x32_bf16(a1, bq1, z, 0, 0, 0);
    }
  } else {
    const unsigned short* kp = K8 + ((long)b * 16 + fr) * DD + hoff + g * 8;
    bf16x8 a0 = *(const bf16x8*)(kp);
    bf16x8 a1 = *(const bf16x8*)(kp + 32);
    f32x4 z = {0.f, 0.f, 0.f, 0.f};
    z = __builtin_amdgcn_mfma_f32_16x16x32_bf16(a0, bq0, z, 0, 0, 0);
    st[0] = __builtin_amdgcn_mfma_f32_16x16x32_bf16(a1, bq1, z, 0, 0, 0);
    st[1] = f32x4{0.f, 0.f, 0.f, 0.f};
  }

  float m = -3.0e38f;
#pragma unroll
  for (int kt = 0; kt < 2; ++kt)
#pragma unroll
    for (int r = 0; r < 4; ++r) {
      int idx = kt * 16 + g * 4 + r;
      bool valid;
      if (MODE == 0) {
        int rel = kstart + idx - qbase - fr;
        valid = (rel >= -8) && (rel <= 8);
      } else {
        valid = (idx < 8);
      }
      float s = valid ? st[kt][r] * 0.125f : -1.0e30f;
      st[kt][r] = s;
      m = fmaxf(m, s);
    }
  m = fmaxf(m, __shfl_xor(m, 16, 64));
  m = fmaxf(m, __shfl_xor(m, 32, 64));

  float lsum = 0.f;
#pragma unroll
  for (int kt = 0; kt < 2; ++kt)
#pragma unroll
    for (int r = 0; r < 4; ++r) {
      float e = __expf(st[kt][r] - m);
      st[kt][r] = e;
      lsum += e;
    }
  lsum += __shfl_xor(lsum, 16, 64);
  lsum += __shfl_xor(lsum, 32, 64);

  unsigned short* pl = &P_lds[w][fr * 40 + g * 4];
#pragma unroll
  for (int kt = 0; kt < 2; ++kt) {
    uint2 pk;
    pk.x = (unsigned)f2b(st[kt][0]) | ((unsigned)f2b(st[kt][1]) << 16);
    pk.y = (unsigned)f2b(st[kt][2]) | ((unsigned)f2b(st[kt][3]) << 16);
    *(uint2*)(pl + kt * 16) = pk;
  }

  f32x4 oacc[4];
#pragma unroll
  for (int mf = 0; mf < 4; ++mf)
#pragma unroll
    for (int r = 0; r < 4; ++r) oacc[mf][r] = 0.f;

  const unsigned short* pr = &P_lds[w][fr * 40 + g * 8];
  bf16x8 pf = *(const bf16x8*)(pr);
  long kb2 = (MODE == 0) ? kstart : 0;
#pragma unroll
  for (int mf = 0; mf < 4; ++mf) {
    const unsigned short* vp =
        Vt + ((long)b * DD + hoff + mf * 16 + fr) * VSTR + kb2 + g * 8;
    bf16x8 vf = *(const bf16x8*)(vp);
    oacc[mf] = __builtin_amdgcn_mfma_f32_16x16x32_bf16(vf, pf, oacc[mf], 0, 0, 0);
  }

  float inv = 1.f / lsum;
  float* orow = Outp + qrow * DD + hoff;
#pragma unroll
  for (int mf = 0; mf < 4; ++mf) {
    f32x4 ov;
#pragma unroll
    for (int r = 0; r < 4; ++r) ov[r] = oacc[mf][r] * inv;
    *(f32x4*)(orow + mf * 16 + g * 4) = ov;
  }
}

// ---------------- layernorm + gate scale + concat to bf16 -------------------
__global__ __launch_bounds__(256) void ln_gate_concat(
    const float* __restrict__ gsrc, const float* __restrict__ lsrc, const float* __restrict__ tsrc,
    const float* __restrict__ gg, const float* __restrict__ gb,
    const float* __restrict__ lgam, const float* __restrict__ lbet,
    const float* __restrict__ tg, const float* __restrict__ tb,
    const float* __restrict__ fw, unsigned short* __restrict__ comb) {
  int row = blockIdx.x;
  int b = row >> 11;
  int tid = threadIdx.x;
  __shared__ float red[8];
  const float* srcs[3] = {gsrc, lsrc, tsrc};
  const float* gams[3] = {gg, lgam, tg};
  const float* bets[3] = {gb, lbet, tb};
#pragma unroll
  for (int br = 0; br < 3; ++br) {
    const float* src = srcs[br] + (long)row * DD;
    float x0 = src[tid], x1 = src[tid + 256], x2 = src[tid + 512];
    float s = x0 + x1 + x2;
    float ss = x0 * x0 + x1 * x1 + x2 * x2;
#pragma unroll
    for (int msk = 1; msk < 64; msk <<= 1) {
      s += __shfl_xor(s, msk, 64);
      ss += __shfl_xor(ss, msk, 64);
    }
    int wv = tid >> 6, lane = tid & 63;
    if (lane == 0) { red[wv] = s; red[4 + wv] = ss; }
    __syncthreads();
    float S4 = red[0] + red[1] + red[2] + red[3];
    float SQ = red[4] + red[5] + red[6] + red[7];
    float mean = S4 * (1.f / (float)DD);
    float var = SQ * (1.f / (float)DD) - mean * mean;
    float rs = rsqrtf(var + 1e-5f);
    float gate = fw[b * 3 + br];
    const float* gam = gams[br];
    const float* bet = bets[br];
    unsigned short* dst = comb + (long)row * 2304 + br * DD;
    dst[tid]       = f2b(((x0 - mean) * rs * gam[tid]       + bet[tid])       * gate);
    dst[tid + 256] = f2b(((x1 - mean) * rs * gam[tid + 256] + bet[tid + 256]) * gate);
    dst[tid + 512] = f2b(((x2 - mean) * rs * gam[tid + 512] + bet[tid + 512]) * gate);
    __syncthreads();
  }
}

// ---------------- launcher ---------------------------------------------------
extern "C" void kernel_launch(void* const* d_in, const int* in_sizes, int n_in,
                              void* d_out, int out_size, void* d_ws, size_t ws_size,
                              hipStream_t stream) {
  const float* x        = (const float*)d_in[0];
  const float* wgq      = (const float*)d_in[1];
  const float* wgk      = (const float*)d_in[2];
  const float* wgv      = (const float*)d_in[3];
  const float* wlq      = (const float*)d_in[4];
  const float* wlk      = (const float*)d_in[5];
  const float* wlv      = (const float*)d_in[6];
  const float* wtq      = (const float*)d_in[7];
  const float* wtk      = (const float*)d_in[8];
  const float* wtv      = (const float*)d_in[9];
  const float* w_out    = (const float*)d_in[10];
  const float* b_out    = (const float*)d_in[11];
  const float* w_gate   = (const float*)d_in[12];
  const float* b_gate   = (const float*)d_in[13];
  const float* w_sparse = (const float*)d_in[14];
  const float* b_sparse = (const float*)d_in[15];
  const float* g_gamma  = (const float*)d_in[16];
  const float* g_beta   = (const float*)d_in[17];
  const float* l_gamma  = (const float*)d_in[18];
  const float* l_beta   = (const float*)d_in[19];
  const float* t_gamma  = (const float*)d_in[20];
  const float* t_beta   = (const float*)d_in[21];
  float* outp = (float*)d_out;

  unsigned short* xb   = (unsigned short*)d_ws;
  unsigned short* xpb  = xb  + (long)NTOK * DD;
  unsigned short* WTx  = xpb + (long)NTOK * DD;
  unsigned short* WTt  = WTx + (long)4608 * DD;
  unsigned short* WTo  = WTt + (long)2304 * DD;
  unsigned short* QKVx = WTo + (long)DD * 2304;
  unsigned short* QKVt = QKVx + (long)NTOK * 4608;
  unsigned short* comb = QKVt + (long)NTOK * 2304;
  float* gout    = (float*)(comb + (long)NTOK * 2304);
  float* lout    = gout + (long)NTOK * DD;
  float* tout    = lout + (long)NTOK * DD;
  float* imp     = tout + (long)NTOK * DD;
  float* partial = imp + NTOK;
  float* fw      = partial + 32 * DD;
  int*   sel     = (int*)(fw + 8);
  unsigned short* Kg = (unsigned short*)(sel + 832);     // [2][448][768]
  unsigned short* Vt = Kg + (long)BB * KPAD * DD;        // [2][768][448]
  // buffer reuse (stream-ordered; xb/xpb dead after the projection GEMMs):
  unsigned short* Vtl = xpb;                             // [2][768][2048]
  unsigned short* K8  = xb;                              // [2][16][768]
  unsigned short* Vt8 = xb + (long)BB * 16 * DD;         // [2][768][32]

  prep_imp<<<NTOK, 256, 0, stream>>>(x, w_sparse, b_sparse, xb, xpb, imp);
  transpose_all<<<dim3(24, 72, 10), dim3(32, 8), 0, stream>>>(
      wgq, wgk, wgv, wlq, wlk, wlv, wtq, wtk, wtv, w_out, WTx, WTt, WTo);
  topk_kernel<<<BB, 1024, 0, stream>>>(imp, sel);
  gate1<<<dim3(16, BB), 256, 0, stream>>>(x, partial);
  gate2<<<BB, 256, 0, stream>>>(partial, w_gate, b_gate, fw);

  gemm_tile<1><<<dim3(36, 32), 256, 0, stream>>>(xb,  WTx, QKVx, nullptr, 4608, DD);
  gemm_tile<1><<<dim3(18, 32), 256, 0, stream>>>(xpb, WTt, QKVt, nullptr, 2304, DD);

  gather_k<<<dim3(KPAD, BB), 256, 0, stream>>>(QKVx, sel, Kg);
  gather_vt<<<dim3(28, 12, BB), 256, 0, stream>>>(QKVx, sel, Vt);
  attn_global_flash<<<dim3(32, BB * HH), 256, 0, stream>>>(QKVx, Kg, Vt, gout);

  transpose_vl<<<dim3(128, 12, BB), 256, 0, stream>>>(QKVx, Vtl);
  gather_t8<<<dim3(3, BB), 256, 0, stream>>>(QKVt, K8, Vt8);
  attn_win_mfma<0><<<dim3(32, BB * HH), 256, 0, stream>>>(QKVx, nullptr, Vtl, lout);
  attn_win_mfma<1><<<dim3(32, BB * HH), 256, 0, stream>>>(QKVt, K8, Vt8, tout);

  ln_gate_concat<<<NTOK, 256, 0, stream>>>(gout, lout, tout, g_gamma, g_beta,
                                           l_gamma, l_beta, t_gamma, t_beta, fw, comb);
  gemm_tile<0><<<dim3(6, 32), 256, 0, stream>>>(comb, WTo, outp, b_out, 768, 2304);
}